// Round 1
// baseline (7544.514 us; speedup 1.0000x reference)
//
#include <hip/hip_runtime.h>
#include <math.h>

#define BM 128
#define BN 128
#define BKT 16

// ---------------- block-wide sum reduce (256 threads = 4 waves) ----------------
__device__ __forceinline__ float block_reduce_sum(float v, float* sb) {
#pragma unroll
  for (int o = 32; o > 0; o >>= 1) v += __shfl_down(v, o, 64);
  const int t = threadIdx.x;
  if ((t & 63) == 0) sb[t >> 6] = v;
  __syncthreads();
  v = sb[0] + sb[1] + sb[2] + sb[3];
  __syncthreads();
  return v;
}

// ---------------- fp32 tiled GEMM: C = A[M,K] @ W[K,N] + bias (+epilogue) ------
// EPI: 0 = bias only, 1 = bias + exact GELU, 2 = bias + residual add
template <int EPI>
__global__ __launch_bounds__(256, 2) void gemm_f32(
    const float* __restrict__ A, const float* __restrict__ W,
    const float* __restrict__ bias, const float* __restrict__ res,
    float* __restrict__ C, int M, int N, int K) {
  __shared__ float As[BKT][BM];  // k-major (transposed A tile)
  __shared__ float Bs[BKT][BN];

  const int t = threadIdx.x;
  const int tx = t & 15, ty = t >> 4;
  const int bm = blockIdx.y * BM, bn = blockIdx.x * BN;

  // staging maps
  const int arow = t >> 2;          // 0..63
  const int akq = (t & 3) << 2;     // 0,4,8,12
  const int bkr = t >> 5;           // 0..7
  const int bc = (t & 31) << 2;     // 0..124

  const float* Ap0 = A + (size_t)(bm + arow) * K + akq;
  const float* Ap1 = Ap0 + (size_t)64 * K;
  const float* Wp0 = W + (size_t)bkr * N + bn + bc;
  const float* Wp1 = Wp0 + (size_t)8 * N;

  float acc[8][8];
#pragma unroll
  for (int i = 0; i < 8; ++i)
#pragma unroll
    for (int j = 0; j < 8; ++j) acc[i][j] = 0.f;

  for (int k0 = 0; k0 < K; k0 += BKT) {
    const float4 a0 = *(const float4*)(Ap0 + k0);
    const float4 a1 = *(const float4*)(Ap1 + k0);
    const float4 b0 = *(const float4*)(Wp0 + (size_t)k0 * N);
    const float4 b1 = *(const float4*)(Wp1 + (size_t)k0 * N);
    __syncthreads();
    As[akq + 0][arow] = a0.x; As[akq + 1][arow] = a0.y;
    As[akq + 2][arow] = a0.z; As[akq + 3][arow] = a0.w;
    As[akq + 0][arow + 64] = a1.x; As[akq + 1][arow + 64] = a1.y;
    As[akq + 2][arow + 64] = a1.z; As[akq + 3][arow + 64] = a1.w;
    *(float4*)&Bs[bkr][bc] = b0;
    *(float4*)&Bs[bkr + 8][bc] = b1;
    __syncthreads();
#pragma unroll
    for (int k = 0; k < BKT; ++k) {
      const float4 xa0 = *(const float4*)&As[k][ty * 8];
      const float4 xa1 = *(const float4*)&As[k][ty * 8 + 4];
      const float4 xb0 = *(const float4*)&Bs[k][tx * 8];
      const float4 xb1 = *(const float4*)&Bs[k][tx * 8 + 4];
      const float av[8] = {xa0.x, xa0.y, xa0.z, xa0.w, xa1.x, xa1.y, xa1.z, xa1.w};
      const float bv[8] = {xb0.x, xb0.y, xb0.z, xb0.w, xb1.x, xb1.y, xb1.z, xb1.w};
#pragma unroll
      for (int i = 0; i < 8; ++i)
#pragma unroll
        for (int j = 0; j < 8; ++j) acc[i][j] = fmaf(av[i], bv[j], acc[i][j]);
    }
  }

#pragma unroll
  for (int i = 0; i < 8; ++i) {
    const size_t row = (size_t)(bm + ty * 8 + i);
#pragma unroll
    for (int j4 = 0; j4 < 2; ++j4) {
      const int n = bn + tx * 8 + j4 * 4;
      float4 v;
      v.x = acc[i][j4 * 4 + 0] + bias[n + 0];
      v.y = acc[i][j4 * 4 + 1] + bias[n + 1];
      v.z = acc[i][j4 * 4 + 2] + bias[n + 2];
      v.w = acc[i][j4 * 4 + 3] + bias[n + 3];
      if (EPI == 1) {
        v.x = 0.5f * v.x * (1.f + erff(v.x * 0.70710678118654752f));
        v.y = 0.5f * v.y * (1.f + erff(v.y * 0.70710678118654752f));
        v.z = 0.5f * v.z * (1.f + erff(v.z * 0.70710678118654752f));
        v.w = 0.5f * v.w * (1.f + erff(v.w * 0.70710678118654752f));
      }
      if (EPI == 2) {
        const float4 r = *(const float4*)(res + row * N + n);
        v.x += r.x; v.y += r.y; v.z += r.z; v.w += r.w;
      }
      *(float4*)(C + row * N + n) = v;
    }
  }
}

// ---------------- LayerNorm over rows of 1024 ----------------
__global__ __launch_bounds__(256) void ln_kernel(
    const float* __restrict__ X, const float* __restrict__ g,
    const float* __restrict__ bt, float* __restrict__ out) {
  __shared__ float sb[4];
  const int row = blockIdx.x, t = threadIdx.x;
  const float4 x = *(const float4*)&X[(size_t)row * 1024 + t * 4];
  const float s = block_reduce_sum(x.x + x.y + x.z + x.w, sb);
  const float mu = s * (1.f / 1024.f);
  const float dx = x.x - mu, dy = x.y - mu, dz = x.z - mu, dw = x.w - mu;
  const float ss = block_reduce_sum(dx * dx + dy * dy + dz * dz + dw * dw, sb);
  const float rs = rsqrtf(ss * (1.f / 1024.f) + 1e-12f);
  const float4 gv = *(const float4*)&g[t * 4];
  const float4 bv = *(const float4*)&bt[t * 4];
  float4 o;
  o.x = dx * rs * gv.x + bv.x;
  o.y = dy * rs * gv.y + bv.y;
  o.z = dz * rs * gv.z + bv.z;
  o.w = dw * rs * gv.w + bv.w;
  *(float4*)&out[(size_t)row * 1024 + t * 4] = o;
}

// ---------------- fused flash attention per (b, h) ----------------
// Q/K/V in [B,S,H] layout (head h = cols h*32..h*32+31). rel_l: [1023, 32].
__global__ __launch_bounds__(256, 1) void attn_kernel(
    const float* __restrict__ Q, const float* __restrict__ Km,
    const float* __restrict__ Vm, const float* __restrict__ mask,
    const float* __restrict__ rel_l, float* __restrict__ ctxout) {
  __shared__ float Ks[512][32];
  __shared__ float Vs[512][32];
  __shared__ float rel_s[1023];
  __shared__ float madd[512];

  const int h = blockIdx.x, b = blockIdx.y;
  const int t = threadIdx.x;
  const float SCALE = 0.17677669529663687f;  // 1/sqrt(32)

#pragma unroll
  for (int i = 0; i < 16; ++i) {
    const int f = t + i * 256;  // 0..4095
    const int row = f >> 3, c4 = (f & 7) << 2;
    const size_t gofs = (size_t)(b * 512 + row) * 1024 + h * 32 + c4;
    *(float4*)&Ks[row][c4] = *(const float4*)&Km[gofs];
    *(float4*)&Vs[row][c4] = *(const float4*)&Vm[gofs];
  }
  for (int i = t; i < 1023; i += 256) rel_s[i] = rel_l[(size_t)i * 32 + h];
  for (int i = t; i < 512; i += 256) madd[i] = (1.f - mask[b * 512 + i]) * -1e9f;
  __syncthreads();

  const int qr0 = t, qr1 = t + 256;
  float4 q0v[8], q1v[8];
  const float* qb0 = Q + (size_t)(b * 512 + qr0) * 1024 + h * 32;
  const float* qb1 = Q + (size_t)(b * 512 + qr1) * 1024 + h * 32;
#pragma unroll
  for (int i = 0; i < 8; ++i) {
    q0v[i] = *(const float4*)(qb0 + i * 4);
    q1v[i] = *(const float4*)(qb1 + i * 4);
  }

  float c0[32], c1[32];
#pragma unroll
  for (int d = 0; d < 32; ++d) { c0[d] = 0.f; c1[d] = 0.f; }
  float m0 = -INFINITY, m1 = -INFINITY, l0 = 0.f, l1 = 0.f;

  for (int k = 0; k < 512; ++k) {
    float s0 = 0.f, s1 = 0.f;
#pragma unroll
    for (int i = 0; i < 8; ++i) {
      const float4 kk = *(const float4*)&Ks[k][i * 4];
      const float4 a0 = q0v[i], a1 = q1v[i];
      s0 += a0.x * kk.x + a0.y * kk.y + a0.z * kk.z + a0.w * kk.w;
      s1 += a1.x * kk.x + a1.y * kk.y + a1.z * kk.z + a1.w * kk.w;
    }
    const float ma = madd[k];
    s0 = fmaf(s0 + rel_s[qr0 - k + 511], SCALE, ma);
    s1 = fmaf(s1 + rel_s[qr1 - k + 511], SCALE, ma);
    if (s0 > m0) {
      const float al = __expf(m0 - s0);
      l0 *= al;
#pragma unroll
      for (int d = 0; d < 32; ++d) c0[d] *= al;
      m0 = s0;
    }
    if (s1 > m1) {
      const float al = __expf(m1 - s1);
      l1 *= al;
#pragma unroll
      for (int d = 0; d < 32; ++d) c1[d] *= al;
      m1 = s1;
    }
    const float p0 = __expf(s0 - m0);
    const float p1 = __expf(s1 - m1);
    l0 += p0; l1 += p1;
#pragma unroll
    for (int i = 0; i < 8; ++i) {
      const float4 vv = *(const float4*)&Vs[k][i * 4];
      c0[i * 4 + 0] = fmaf(p0, vv.x, c0[i * 4 + 0]);
      c0[i * 4 + 1] = fmaf(p0, vv.y, c0[i * 4 + 1]);
      c0[i * 4 + 2] = fmaf(p0, vv.z, c0[i * 4 + 2]);
      c0[i * 4 + 3] = fmaf(p0, vv.w, c0[i * 4 + 3]);
      c1[i * 4 + 0] = fmaf(p1, vv.x, c1[i * 4 + 0]);
      c1[i * 4 + 1] = fmaf(p1, vv.y, c1[i * 4 + 1]);
      c1[i * 4 + 2] = fmaf(p1, vv.z, c1[i * 4 + 2]);
      c1[i * 4 + 3] = fmaf(p1, vv.w, c1[i * 4 + 3]);
    }
  }

  const float inv0 = 1.f / l0, inv1 = 1.f / l1;
  float* o0 = ctxout + (size_t)(b * 512 + qr0) * 1024 + h * 32;
  float* o1 = ctxout + (size_t)(b * 512 + qr1) * 1024 + h * 32;
#pragma unroll
  for (int i = 0; i < 8; ++i) {
    float4 o;
    o.x = c0[i * 4 + 0] * inv0; o.y = c0[i * 4 + 1] * inv0;
    o.z = c0[i * 4 + 2] * inv0; o.w = c0[i * 4 + 3] * inv0;
    *(float4*)(o0 + i * 4) = o;
    o.x = c1[i * 4 + 0] * inv1; o.y = c1[i * 4 + 1] * inv1;
    o.z = c1[i * 4 + 2] * inv1; o.w = c1[i * 4 + 3] * inv1;
    *(float4*)(o1 + i * 4) = o;
  }
}

// ---------------- pooling: mean + max + first token ----------------
__global__ __launch_bounds__(128) void pool_kernel(
    const float* __restrict__ X, const float* __restrict__ mask,
    float* __restrict__ pooled) {
  const int b = blockIdx.y;
  const int col = blockIdx.x * 128 + threadIdx.x;
  float sum = 0.f, mx = -INFINITY, cnt = 0.f;
  for (int s = 0; s < 512; ++s) {
    const float v = X[(size_t)(b * 512 + s) * 1024 + col];
    const float mk = mask[b * 512 + s];
    sum = fmaf(v, mk, sum);
    cnt += mk;
    mx = fmaxf(mx, v + (1.f - mk) * -1e9f);
  }
  pooled[(size_t)b * 3072 + col] = sum / cnt;
  pooled[(size_t)b * 3072 + 1024 + col] = mx;
  pooled[(size_t)b * 3072 + 2048 + col] = X[(size_t)(b * 512) * 1024 + col];
}

// ---------------- small pooled GEMM [8,3072]@[3072,1024] ----------------
__global__ __launch_bounds__(256) void pool_gemm_kernel(
    const float* __restrict__ P, const float* __restrict__ W,
    const float* __restrict__ bias, float* __restrict__ out) {
  const int idx = blockIdx.x * 256 + threadIdx.x;  // 0..8191
  const int b = idx >> 10, n = idx & 1023;
  const float* pr = P + (size_t)b * 3072;
  float a = 0.f;
  for (int k = 0; k < 3072; ++k) a = fmaf(pr[k], W[(size_t)k * 1024 + n], a);
  out[idx] = a + bias[n];
}

// ---------------- classifier [8,1024]@[1024,20] ----------------
__global__ __launch_bounds__(64) void cls_kernel(
    const float* __restrict__ X, const float* __restrict__ W,
    const float* __restrict__ bias, float* __restrict__ out) {
  const int b = blockIdx.x, n = threadIdx.x;
  if (n < 20) {
    float a = 0.f;
    for (int k = 0; k < 1024; ++k) a = fmaf(X[(size_t)b * 1024 + k], W[(size_t)k * 20 + n], a);
    out[b * 20 + n] = a + bias[n];
  }
}

extern "C" void kernel_launch(void* const* d_in, const int* in_sizes, int n_in,
                              void* d_out, int out_size, void* d_ws, size_t ws_size,
                              hipStream_t stream) {
  const float* hs    = (const float*)d_in[0];
  const float* amask = (const float*)d_in[1];
  const float* Wq    = (const float*)d_in[2];
  const float* bq    = (const float*)d_in[3];
  const float* Wk    = (const float*)d_in[4];
  const float* bk    = (const float*)d_in[5];
  const float* Wv    = (const float*)d_in[6];
  const float* bv    = (const float*)d_in[7];
  const float* Wo    = (const float*)d_in[8];
  const float* bo    = (const float*)d_in[9];
  const float* ln1g  = (const float*)d_in[10];
  const float* ln1b  = (const float*)d_in[11];
  const float* W1    = (const float*)d_in[12];
  const float* b1    = (const float*)d_in[13];
  const float* W2    = (const float*)d_in[14];
  const float* b2    = (const float*)d_in[15];
  const float* ln2g  = (const float*)d_in[16];
  const float* ln2b  = (const float*)d_in[17];
  const float* rel   = (const float*)d_in[18];
  const float* poolW = (const float*)d_in[19];
  const float* poolb = (const float*)d_in[20];
  const float* plng  = (const float*)d_in[21];
  const float* plnb  = (const float*)d_in[22];
  const float* clsW  = (const float*)d_in[23];
  const float* clsb  = (const float*)d_in[24];

  float* ws = (float*)d_ws;
  const size_t T16 = (size_t)4096 * 1024;  // 16 MB of floats
  float* buf_x   = ws;               // layer output (next layer input)
  float* buf_q   = ws + 1 * T16;
  float* buf_k   = ws + 2 * T16;
  float* buf_v   = ws + 3 * T16;
  float* buf_ctx = ws + 4 * T16;
  float* buf_t   = ws + 5 * T16;
  float* buf_h1  = ws + 6 * T16;
  float* buf_ffn = ws + 1 * T16;     // aliases q/k/v/ctx (dead by FFN time)
  float* pooled  = ws + 7 * T16;
  float* pool_h  = pooled + 8 * 3072;
  float* pool_h2 = pool_h + 8 * 1024;

  const dim3 gP(1024 / BN, 4096 / BM);  // projections: N=1024
  const dim3 gF(4096 / BN, 4096 / BM);  // FFN1: N=4096

  const float* x_in = hs;
  for (int l = 0; l < 4; ++l) {
    const float* Wq_l = Wq + (size_t)l * 1024 * 1024;
    const float* Wk_l = Wk + (size_t)l * 1024 * 1024;
    const float* Wv_l = Wv + (size_t)l * 1024 * 1024;
    const float* Wo_l = Wo + (size_t)l * 1024 * 1024;
    const float* W1_l = W1 + (size_t)l * 1024 * 4096;
    const float* W2_l = W2 + (size_t)l * 4096 * 1024;

    gemm_f32<0><<<gP, 256, 0, stream>>>(x_in, Wq_l, bq + l * 1024, nullptr, buf_q, 4096, 1024, 1024);
    gemm_f32<0><<<gP, 256, 0, stream>>>(x_in, Wk_l, bk + l * 1024, nullptr, buf_k, 4096, 1024, 1024);
    gemm_f32<0><<<gP, 256, 0, stream>>>(x_in, Wv_l, bv + l * 1024, nullptr, buf_v, 4096, 1024, 1024);

    attn_kernel<<<dim3(32, 8), 256, 0, stream>>>(buf_q, buf_k, buf_v, amask,
                                                 rel + (size_t)l * 1023 * 32, buf_ctx);

    gemm_f32<2><<<gP, 256, 0, stream>>>(buf_ctx, Wo_l, bo + l * 1024, x_in, buf_t, 4096, 1024, 1024);
    ln_kernel<<<4096, 256, 0, stream>>>(buf_t, ln1g + l * 1024, ln1b + l * 1024, buf_h1);

    gemm_f32<1><<<gF, 256, 0, stream>>>(buf_h1, W1_l, b1 + l * 4096, nullptr, buf_ffn, 4096, 4096, 1024);
    gemm_f32<2><<<gP, 256, 0, stream>>>(buf_ffn, W2_l, b2 + l * 1024, buf_h1, buf_t, 4096, 1024, 4096);
    ln_kernel<<<4096, 256, 0, stream>>>(buf_t, ln2g + l * 1024, ln2b + l * 1024, buf_x);
    x_in = buf_x;
  }

  pool_kernel<<<dim3(8, 8), 128, 0, stream>>>(buf_x, amask, pooled);
  pool_gemm_kernel<<<32, 256, 0, stream>>>(pooled, poolW, poolb, pool_h);
  ln_kernel<<<8, 256, 0, stream>>>(pool_h, plng, plnb, pool_h2);
  cls_kernel<<<8, 64, 0, stream>>>(pool_h2, clsW, clsb, (float*)d_out);
}

// Round 2
// 4041.598 us; speedup vs baseline: 1.8667x; 1.8667x over previous
//
#include <hip/hip_runtime.h>
#include <math.h>

typedef __attribute__((ext_vector_type(8))) short bf16x8;
typedef __attribute__((ext_vector_type(4))) float f32x4;

// ---------- bf16 helpers (RNE) ----------
__device__ __forceinline__ ushort f2bf(float x) {
  unsigned u = __float_as_uint(x);
  return (ushort)((u + 0x7FFFu + ((u >> 16) & 1u)) >> 16);
}
__device__ __forceinline__ float bf2f(ushort h) {
  return __uint_as_float(((unsigned)h) << 16);
}

// ---------- async global->LDS 16B ----------
__device__ __forceinline__ void gl_lds16(const ushort* g, ushort* l) {
  __builtin_amdgcn_global_load_lds(
      (const __attribute__((address_space(1))) unsigned int*)g,
      (__attribute__((address_space(3))) unsigned int*)l, 16, 0, 0);
}

// ---------- block-wide sum reduce (256 threads = 4 waves) ----------
__device__ __forceinline__ float block_reduce_sum(float v, float* sb) {
#pragma unroll
  for (int o = 32; o > 0; o >>= 1) v += __shfl_down(v, o, 64);
  const int t = threadIdx.x;
  if ((t & 63) == 0) sb[t >> 6] = v;
  __syncthreads();
  v = sb[0] + sb[1] + sb[2] + sb[3];
  __syncthreads();
  return v;
}

// ---------- activation split: fp32 -> (hi, lo) bf16 planes ----------
__global__ __launch_bounds__(256) void asplit(const float* __restrict__ X,
                                              ushort* __restrict__ H,
                                              ushort* __restrict__ L, int n4) {
  const int i = blockIdx.x * 256 + threadIdx.x;
  if (i >= n4) return;
  const float4 x = ((const float4*)X)[i];
  ushort4 h, l;
  h.x = f2bf(x.x); l.x = f2bf(x.x - bf2f(h.x));
  h.y = f2bf(x.y); l.y = f2bf(x.y - bf2f(h.y));
  h.z = f2bf(x.z); l.z = f2bf(x.z - bf2f(h.z));
  h.w = f2bf(x.w); l.w = f2bf(x.w - bf2f(h.w));
  ((ushort4*)H)[i] = h;
  ((ushort4*)L)[i] = l;
}

// ---------- weight transpose+split: W[K,N] fp32 -> Th,Tl [N,K] bf16 ----------
__global__ __launch_bounds__(256) void wsplit_t(const float* __restrict__ W,
                                                ushort* __restrict__ Th,
                                                ushort* __restrict__ Tl,
                                                int K, int N) {
  __shared__ float s[32][33];
  const int tx = threadIdx.x & 31, ty = threadIdx.x >> 5;
  const int n0 = blockIdx.x * 32, k0 = blockIdx.y * 32;
#pragma unroll
  for (int i = 0; i < 4; ++i)
    s[ty + i * 8][tx] = W[(size_t)(k0 + ty + i * 8) * N + n0 + tx];
  __syncthreads();
#pragma unroll
  for (int i = 0; i < 4; ++i) {
    const int n = ty + i * 8;
    const float x = s[tx][n];
    const ushort h = f2bf(x);
    const size_t o = (size_t)(n0 + n) * K + k0 + tx;
    Th[o] = h;
    Tl[o] = f2bf(x - bf2f(h));
  }
}

// ---------- split-bf16 MFMA GEMM: C = (Ah+Al)[M,K] @ (Bh+Bl)^T[N,K] + bias ----
// 128x64 tile, 4 waves of 64x32, BK=32, 3 MFMA passes (drop lo*lo).
// EPI: 0 = bias -> C;  1 = bias+GELU -> split planes Oh/Ol;  2 = bias+res -> C
template <int EPI>
__global__ __launch_bounds__(256, 2) void gemm_bf16s(
    const ushort* __restrict__ Ah, const ushort* __restrict__ Al,
    const ushort* __restrict__ Bh, const ushort* __restrict__ Bl,
    const float* __restrict__ bias, const float* __restrict__ res,
    float* __restrict__ C, ushort* __restrict__ Oh, ushort* __restrict__ Ol,
    int M, int N, int K) {
  // slab layout [k8][m][8]: conflict-free b128 reads + linear global_load_lds
  __shared__ __align__(16) ushort Ash[4096], Asl[4096], Bsh[2048], Bsl[2048];
  const int t = threadIdx.x;
  const int w = t >> 6, lane = t & 63;
  const int bm = blockIdx.y * 128, bn = blockIdx.x * 64;
  const int wm = w >> 1, wn = w & 1;

  const ushort* pAh0 = Ah + (size_t)(bm + lane) * K + w * 8;
  const ushort* pAh1 = pAh0 + (size_t)64 * K;
  const ushort* pAl0 = Al + (size_t)(bm + lane) * K + w * 8;
  const ushort* pAl1 = pAl0 + (size_t)64 * K;
  const ushort* pBh = Bh + (size_t)(bn + lane) * K + w * 8;
  const ushort* pBl = Bl + (size_t)(bn + lane) * K + w * 8;

  ushort* dA0 = &Ash[w * 1024];
  ushort* dA1 = &Ash[w * 1024 + 512];
  ushort* dA0l = &Asl[w * 1024];
  ushort* dA1l = &Asl[w * 1024 + 512];
  ushort* dB = &Bsh[w * 512];
  ushort* dBl = &Bsl[w * 512];

  const int lhi = lane >> 4, llo = lane & 15;
  const ushort* rA_h = &Ash[lhi * 1024 + (wm * 64 + llo) * 8];
  const ushort* rA_l = &Asl[lhi * 1024 + (wm * 64 + llo) * 8];
  const ushort* rB_h = &Bsh[lhi * 512 + (wn * 32 + llo) * 8];
  const ushort* rB_l = &Bsl[lhi * 512 + (wn * 32 + llo) * 8];

  f32x4 acc[4][2] = {};

  for (int k0 = 0; k0 < K; k0 += 32) {
    __syncthreads();  // previous compute done before LDS overwrite
    gl_lds16(pAh0 + k0, dA0);
    gl_lds16(pAh1 + k0, dA1);
    gl_lds16(pAl0 + k0, dA0l);
    gl_lds16(pAl1 + k0, dA1l);
    gl_lds16(pBh + k0, dB);
    gl_lds16(pBl + k0, dBl);
    __syncthreads();  // vmcnt drained by barrier -> staging visible

    bf16x8 ah[4], al[4], bh[2], bl[2];
#pragma unroll
    for (int fm = 0; fm < 4; ++fm) {
      ah[fm] = *(const bf16x8*)(rA_h + fm * 128);
      al[fm] = *(const bf16x8*)(rA_l + fm * 128);
    }
#pragma unroll
    for (int fn = 0; fn < 2; ++fn) {
      bh[fn] = *(const bf16x8*)(rB_h + fn * 128);
      bl[fn] = *(const bf16x8*)(rB_l + fn * 128);
    }
#pragma unroll
    for (int fm = 0; fm < 4; ++fm)
#pragma unroll
      for (int fn = 0; fn < 2; ++fn) {
        acc[fm][fn] = __builtin_amdgcn_mfma_f32_16x16x32_bf16(ah[fm], bh[fn], acc[fm][fn], 0, 0, 0);
        acc[fm][fn] = __builtin_amdgcn_mfma_f32_16x16x32_bf16(al[fm], bh[fn], acc[fm][fn], 0, 0, 0);
        acc[fm][fn] = __builtin_amdgcn_mfma_f32_16x16x32_bf16(ah[fm], bl[fn], acc[fm][fn], 0, 0, 0);
      }
  }

  // epilogue: C/D map col = lane&15, row = (lane>>4)*4 + r   [m89-verified]
#pragma unroll
  for (int fm = 0; fm < 4; ++fm)
#pragma unroll
    for (int fn = 0; fn < 2; ++fn) {
#pragma unroll
      for (int r = 0; r < 4; ++r) {
        const int row = bm + wm * 64 + fm * 16 + lhi * 4 + r;
        const int col = bn + wn * 32 + fn * 16 + llo;
        const size_t o = (size_t)row * N + col;
        float v = acc[fm][fn][r] + bias[col];
        if (EPI == 2) v += res[o];
        if (EPI == 1) {
          const float g = 0.5f * v * (1.f + erff(v * 0.70710678118654752f));
          const ushort h = f2bf(g);
          Oh[o] = h;
          Ol[o] = f2bf(g - bf2f(h));
        } else {
          C[o] = v;
        }
      }
    }
}

// ---------- LayerNorm over rows of 1024 ----------
__global__ __launch_bounds__(256) void ln_kernel(
    const float* __restrict__ X, const float* __restrict__ g,
    const float* __restrict__ bt, float* __restrict__ out) {
  __shared__ float sb[4];
  const int row = blockIdx.x, t = threadIdx.x;
  const float4 x = *(const float4*)&X[(size_t)row * 1024 + t * 4];
  const float s = block_reduce_sum(x.x + x.y + x.z + x.w, sb);
  const float mu = s * (1.f / 1024.f);
  const float dx = x.x - mu, dy = x.y - mu, dz = x.z - mu, dw = x.w - mu;
  const float ss = block_reduce_sum(dx * dx + dy * dy + dz * dz + dw * dw, sb);
  const float rs = rsqrtf(ss * (1.f / 1024.f) + 1e-12f);
  const float4 gv = *(const float4*)&g[t * 4];
  const float4 bv = *(const float4*)&bt[t * 4];
  float4 o;
  o.x = dx * rs * gv.x + bv.x;
  o.y = dy * rs * gv.y + bv.y;
  o.z = dz * rs * gv.z + bv.z;
  o.w = dw * rs * gv.w + bv.w;
  *(float4*)&out[(size_t)row * 1024 + t * 4] = o;
}

// ---------- fused flash attention per (b, h) ----------
__global__ __launch_bounds__(256, 1) void attn_kernel(
    const float* __restrict__ Q, const float* __restrict__ Km,
    const float* __restrict__ Vm, const float* __restrict__ mask,
    const float* __restrict__ rel_l, float* __restrict__ ctxout) {
  __shared__ float Ks[512][32];
  __shared__ float Vs[512][32];
  __shared__ float rel_s[1023];
  __shared__ float madd[512];

  const int h = blockIdx.x, b = blockIdx.y;
  const int t = threadIdx.x;
  const float SCALE = 0.17677669529663687f;  // 1/sqrt(32)

#pragma unroll
  for (int i = 0; i < 16; ++i) {
    const int f = t + i * 256;
    const int row = f >> 3, c4 = (f & 7) << 2;
    const size_t gofs = (size_t)(b * 512 + row) * 1024 + h * 32 + c4;
    *(float4*)&Ks[row][c4] = *(const float4*)&Km[gofs];
    *(float4*)&Vs[row][c4] = *(const float4*)&Vm[gofs];
  }
  for (int i = t; i < 1023; i += 256) rel_s[i] = rel_l[(size_t)i * 32 + h];
  for (int i = t; i < 512; i += 256) madd[i] = (1.f - mask[b * 512 + i]) * -1e9f;
  __syncthreads();

  const int qr0 = t, qr1 = t + 256;
  float4 q0v[8], q1v[8];
  const float* qb0 = Q + (size_t)(b * 512 + qr0) * 1024 + h * 32;
  const float* qb1 = Q + (size_t)(b * 512 + qr1) * 1024 + h * 32;
#pragma unroll
  for (int i = 0; i < 8; ++i) {
    q0v[i] = *(const float4*)(qb0 + i * 4);
    q1v[i] = *(const float4*)(qb1 + i * 4);
  }

  float c0[32], c1[32];
#pragma unroll
  for (int d = 0; d < 32; ++d) { c0[d] = 0.f; c1[d] = 0.f; }
  float m0 = -INFINITY, m1 = -INFINITY, l0 = 0.f, l1 = 0.f;

  for (int k = 0; k < 512; ++k) {
    float s0 = 0.f, s1 = 0.f;
#pragma unroll
    for (int i = 0; i < 8; ++i) {
      const float4 kk = *(const float4*)&Ks[k][i * 4];
      const float4 a0 = q0v[i], a1 = q1v[i];
      s0 += a0.x * kk.x + a0.y * kk.y + a0.z * kk.z + a0.w * kk.w;
      s1 += a1.x * kk.x + a1.y * kk.y + a1.z * kk.z + a1.w * kk.w;
    }
    const float ma = madd[k];
    s0 = fmaf(s0 + rel_s[qr0 - k + 511], SCALE, ma);
    s1 = fmaf(s1 + rel_s[qr1 - k + 511], SCALE, ma);
    if (s0 > m0) {
      const float al = __expf(m0 - s0);
      l0 *= al;
#pragma unroll
      for (int d = 0; d < 32; ++d) c0[d] *= al;
      m0 = s0;
    }
    if (s1 > m1) {
      const float al = __expf(m1 - s1);
      l1 *= al;
#pragma unroll
      for (int d = 0; d < 32; ++d) c1[d] *= al;
      m1 = s1;
    }
    const float p0 = __expf(s0 - m0);
    const float p1 = __expf(s1 - m1);
    l0 += p0; l1 += p1;
#pragma unroll
    for (int i = 0; i < 8; ++i) {
      const float4 vv = *(const float4*)&Vs[k][i * 4];
      c0[i * 4 + 0] = fmaf(p0, vv.x, c0[i * 4 + 0]);
      c0[i * 4 + 1] = fmaf(p0, vv.y, c0[i * 4 + 1]);
      c0[i * 4 + 2] = fmaf(p0, vv.z, c0[i * 4 + 2]);
      c0[i * 4 + 3] = fmaf(p0, vv.w, c0[i * 4 + 3]);
      c1[i * 4 + 0] = fmaf(p1, vv.x, c1[i * 4 + 0]);
      c1[i * 4 + 1] = fmaf(p1, vv.y, c1[i * 4 + 1]);
      c1[i * 4 + 2] = fmaf(p1, vv.z, c1[i * 4 + 2]);
      c1[i * 4 + 3] = fmaf(p1, vv.w, c1[i * 4 + 3]);
    }
  }

  const float inv0 = 1.f / l0, inv1 = 1.f / l1;
  float* o0 = ctxout + (size_t)(b * 512 + qr0) * 1024 + h * 32;
  float* o1 = ctxout + (size_t)(b * 512 + qr1) * 1024 + h * 32;
#pragma unroll
  for (int i = 0; i < 8; ++i) {
    float4 o;
    o.x = c0[i * 4 + 0] * inv0; o.y = c0[i * 4 + 1] * inv0;
    o.z = c0[i * 4 + 2] * inv0; o.w = c0[i * 4 + 3] * inv0;
    *(float4*)(o0 + i * 4) = o;
    o.x = c1[i * 4 + 0] * inv1; o.y = c1[i * 4 + 1] * inv1;
    o.z = c1[i * 4 + 2] * inv1; o.w = c1[i * 4 + 3] * inv1;
    *(float4*)(o1 + i * 4) = o;
  }
}

// ---------- pooling: mean + max + first token ----------
__global__ __launch_bounds__(128) void pool_kernel(
    const float* __restrict__ X, const float* __restrict__ mask,
    float* __restrict__ pooled) {
  const int b = blockIdx.y;
  const int col = blockIdx.x * 128 + threadIdx.x;
  float sum = 0.f, mx = -INFINITY, cnt = 0.f;
  for (int s = 0; s < 512; ++s) {
    const float v = X[(size_t)(b * 512 + s) * 1024 + col];
    const float mk = mask[b * 512 + s];
    sum = fmaf(v, mk, sum);
    cnt += mk;
    mx = fmaxf(mx, v + (1.f - mk) * -1e9f);
  }
  pooled[(size_t)b * 3072 + col] = sum / cnt;
  pooled[(size_t)b * 3072 + 1024 + col] = mx;
  pooled[(size_t)b * 3072 + 2048 + col] = X[(size_t)(b * 512) * 1024 + col];
}

// ---------- small pooled GEMM [8,3072]@[3072,1024] ----------
__global__ __launch_bounds__(256) void pool_gemm_kernel(
    const float* __restrict__ P, const float* __restrict__ W,
    const float* __restrict__ bias, float* __restrict__ out) {
  const int idx = blockIdx.x * 256 + threadIdx.x;
  const int b = idx >> 10, n = idx & 1023;
  const float* pr = P + (size_t)b * 3072;
  float a = 0.f;
  for (int k = 0; k < 3072; ++k) a = fmaf(pr[k], W[(size_t)k * 1024 + n], a);
  out[idx] = a + bias[n];
}

// ---------- classifier [8,1024]@[1024,20] ----------
__global__ __launch_bounds__(64) void cls_kernel(
    const float* __restrict__ X, const float* __restrict__ W,
    const float* __restrict__ bias, float* __restrict__ out) {
  const int b = blockIdx.x, n = threadIdx.x;
  if (n < 20) {
    float a = 0.f;
    for (int k = 0; k < 1024; ++k) a = fmaf(X[(size_t)b * 1024 + k], W[(size_t)k * 20 + n], a);
    out[b * 20 + n] = a + bias[n];
  }
}

extern "C" void kernel_launch(void* const* d_in, const int* in_sizes, int n_in,
                              void* d_out, int out_size, void* d_ws, size_t ws_size,
                              hipStream_t stream) {
  const float* hs    = (const float*)d_in[0];
  const float* amask = (const float*)d_in[1];
  const float* Wq    = (const float*)d_in[2];
  const float* bq    = (const float*)d_in[3];
  const float* Wk    = (const float*)d_in[4];
  const float* bk    = (const float*)d_in[5];
  const float* Wv    = (const float*)d_in[6];
  const float* bv    = (const float*)d_in[7];
  const float* Wo    = (const float*)d_in[8];
  const float* bo    = (const float*)d_in[9];
  const float* ln1g  = (const float*)d_in[10];
  const float* ln1b  = (const float*)d_in[11];
  const float* W1    = (const float*)d_in[12];
  const float* b1    = (const float*)d_in[13];
  const float* W2    = (const float*)d_in[14];
  const float* b2    = (const float*)d_in[15];
  const float* ln2g  = (const float*)d_in[16];
  const float* ln2b  = (const float*)d_in[17];
  const float* rel   = (const float*)d_in[18];
  const float* poolW = (const float*)d_in[19];
  const float* poolb = (const float*)d_in[20];
  const float* plng  = (const float*)d_in[21];
  const float* plnb  = (const float*)d_in[22];
  const float* clsW  = (const float*)d_in[23];
  const float* clsb  = (const float*)d_in[24];

  float* ws = (float*)d_ws;
  const size_t T = (size_t)4096 * 1024;  // 16 MB of floats
  float* buf_x   = ws;            // [0,T)
  float* buf_q   = ws + T;        // [T,2T)
  float* buf_k   = ws + 2 * T;
  float* buf_v   = ws + 3 * T;
  float* buf_ctx = ws + 4 * T;
  float* buf_t   = ws + 5 * T;
  float* buf_h1  = ws + 6 * T;
  ushort* P1h = (ushort*)(ws + 7 * T);            // act planes (4M elems each)
  ushort* P1l = P1h + (size_t)4096 * 1024;
  ushort* Wth = (ushort*)(ws + 8 * T);            // weight planes (<=4M each)
  ushort* Wtl = Wth + (size_t)4096 * 1024;
  ushort* P2h = (ushort*)(ws + T);                // FFN planes alias q..ctx (64MB)
  ushort* P2l = P2h + (size_t)4096 * 4096;
  float* pooled  = ws + 9 * T;
  float* pool_h  = pooled + 8 * 3072;
  float* pool_h2 = pool_h + 8 * 1024;

  const int n4act = (4096 * 1024) / 4;  // float4 count of one activation
  const dim3 gemmP(1024 / 64, 4096 / 128);   // N=1024
  const dim3 gemmF1(4096 / 64, 4096 / 128);  // N=4096
  const dim3 wsPP(1024 / 32, 1024 / 32);     // 1024x1024 weights

  const float* x_in = hs;
  for (int l = 0; l < 4; ++l) {
    const float* Wq_l = Wq + (size_t)l * 1024 * 1024;
    const float* Wk_l = Wk + (size_t)l * 1024 * 1024;
    const float* Wv_l = Wv + (size_t)l * 1024 * 1024;
    const float* Wo_l = Wo + (size_t)l * 1024 * 1024;
    const float* W1_l = W1 + (size_t)l * 1024 * 4096;
    const float* W2_l = W2 + (size_t)l * 4096 * 1024;

    asplit<<<n4act / 256, 256, 0, stream>>>(x_in, P1h, P1l, n4act);

    wsplit_t<<<wsPP, 256, 0, stream>>>(Wq_l, Wth, Wtl, 1024, 1024);
    gemm_bf16s<0><<<gemmP, 256, 0, stream>>>(P1h, P1l, Wth, Wtl, bq + l * 1024,
        nullptr, buf_q, nullptr, nullptr, 4096, 1024, 1024);
    wsplit_t<<<wsPP, 256, 0, stream>>>(Wk_l, Wth, Wtl, 1024, 1024);
    gemm_bf16s<0><<<gemmP, 256, 0, stream>>>(P1h, P1l, Wth, Wtl, bk + l * 1024,
        nullptr, buf_k, nullptr, nullptr, 4096, 1024, 1024);
    wsplit_t<<<wsPP, 256, 0, stream>>>(Wv_l, Wth, Wtl, 1024, 1024);
    gemm_bf16s<0><<<gemmP, 256, 0, stream>>>(P1h, P1l, Wth, Wtl, bv + l * 1024,
        nullptr, buf_v, nullptr, nullptr, 4096, 1024, 1024);

    attn_kernel<<<dim3(32, 8), 256, 0, stream>>>(buf_q, buf_k, buf_v, amask,
                                                 rel + (size_t)l * 1023 * 32, buf_ctx);

    asplit<<<n4act / 256, 256, 0, stream>>>(buf_ctx, P1h, P1l, n4act);
    wsplit_t<<<wsPP, 256, 0, stream>>>(Wo_l, Wth, Wtl, 1024, 1024);
    gemm_bf16s<2><<<gemmP, 256, 0, stream>>>(P1h, P1l, Wth, Wtl, bo + l * 1024,
        x_in, buf_t, nullptr, nullptr, 4096, 1024, 1024);
    ln_kernel<<<4096, 256, 0, stream>>>(buf_t, ln1g + l * 1024, ln1b + l * 1024, buf_h1);

    asplit<<<n4act / 256, 256, 0, stream>>>(buf_h1, P1h, P1l, n4act);
    wsplit_t<<<dim3(4096 / 32, 1024 / 32), 256, 0, stream>>>(W1_l, Wth, Wtl, 1024, 4096);
    gemm_bf16s<1><<<gemmF1, 256, 0, stream>>>(P1h, P1l, Wth, Wtl, b1 + l * 4096,
        nullptr, nullptr, P2h, P2l, 4096, 4096, 1024);
    wsplit_t<<<dim3(1024 / 32, 4096 / 32), 256, 0, stream>>>(W2_l, Wth, Wtl, 4096, 1024);
    gemm_bf16s<2><<<gemmP, 256, 0, stream>>>(P2h, P2l, Wth, Wtl, b2 + l * 1024,
        buf_h1, buf_t, nullptr, nullptr, 4096, 1024, 4096);
    ln_kernel<<<4096, 256, 0, stream>>>(buf_t, ln2g + l * 1024, ln2b + l * 1024, buf_x);
    x_in = buf_x;
  }

  pool_kernel<<<dim3(8, 8), 128, 0, stream>>>(buf_x, amask, pooled);
  pool_gemm_kernel<<<32, 256, 0, stream>>>(pooled, poolW, poolb, pool_h);
  ln_kernel<<<8, 256, 0, stream>>>(pool_h, plng, plnb, pool_h2);
  cls_kernel<<<8, 64, 0, stream>>>(pool_h2, clsW, clsb, (float*)d_out);
}

// Round 3
// 3278.928 us; speedup vs baseline: 2.3009x; 1.2326x over previous
//
#include <hip/hip_runtime.h>
#include <math.h>

typedef __attribute__((ext_vector_type(8))) short bf16x8;
typedef __attribute__((ext_vector_type(4))) float f32x4;

// ---------- bf16 helpers (RNE) ----------
__device__ __forceinline__ ushort f2bf(float x) {
  unsigned u = __float_as_uint(x);
  return (ushort)((u + 0x7FFFu + ((u >> 16) & 1u)) >> 16);
}
__device__ __forceinline__ float bf2f(ushort h) {
  return __uint_as_float(((unsigned)h) << 16);
}
__device__ __forceinline__ void gl_lds16(const ushort* g, ushort* l) {
  __builtin_amdgcn_global_load_lds(
      (const __attribute__((address_space(1))) unsigned int*)g,
      (__attribute__((address_space(3))) unsigned int*)l, 16, 0, 0);
}
__device__ __forceinline__ f32x4 mfma32(bf16x8 a, bf16x8 b, f32x4 c) {
  return __builtin_amdgcn_mfma_f32_16x16x32_bf16(a, b, c, 0, 0, 0);
}

// ---------- block-wide sum reduce (256 threads = 4 waves) ----------
__device__ __forceinline__ float block_reduce_sum(float v, float* sb) {
#pragma unroll
  for (int o = 32; o > 0; o >>= 1) v += __shfl_down(v, o, 64);
  const int t = threadIdx.x;
  if ((t & 63) == 0) sb[t >> 6] = v;
  __syncthreads();
  v = sb[0] + sb[1] + sb[2] + sb[3];
  __syncthreads();
  return v;
}

// ---------- activation split: fp32 -> (hi, lo) bf16 planes ----------
__global__ __launch_bounds__(256) void asplit(const float* __restrict__ X,
                                              ushort* __restrict__ H,
                                              ushort* __restrict__ L, int n4) {
  const int i = blockIdx.x * 256 + threadIdx.x;
  if (i >= n4) return;
  const float4 x = ((const float4*)X)[i];
  ushort4 h, l;
  h.x = f2bf(x.x); l.x = f2bf(x.x - bf2f(h.x));
  h.y = f2bf(x.y); l.y = f2bf(x.y - bf2f(h.y));
  h.z = f2bf(x.z); l.z = f2bf(x.z - bf2f(h.z));
  h.w = f2bf(x.w); l.w = f2bf(x.w - bf2f(h.w));
  ((ushort4*)H)[i] = h;
  ((ushort4*)L)[i] = l;
}

// ---------- weight transpose+split: W[K,N] fp32 -> Th,Tl [N,K] bf16 ----------
__global__ __launch_bounds__(256) void wsplit_t(const float* __restrict__ W,
                                                ushort* __restrict__ Th,
                                                ushort* __restrict__ Tl,
                                                int K, int N) {
  __shared__ float s[32][33];
  const int tx = threadIdx.x & 31, ty = threadIdx.x >> 5;
  const int n0 = blockIdx.x * 32, k0 = blockIdx.y * 32;
#pragma unroll
  for (int i = 0; i < 4; ++i)
    s[ty + i * 8][tx] = W[(size_t)(k0 + ty + i * 8) * N + n0 + tx];
  __syncthreads();
#pragma unroll
  for (int i = 0; i < 4; ++i) {
    const int n = ty + i * 8;
    const float x = s[tx][n];
    const ushort h = f2bf(x);
    const size_t o = (size_t)(n0 + n) * K + k0 + tx;
    Th[o] = h;
    Tl[o] = f2bf(x - bf2f(h));
  }
}

// ---------- split-bf16 MFMA GEMM, 128x128 tile, BK=32, 4 waves 2x2 ----------
// EPI: 0 bias->C | 1 bias+GELU->planes | 2 bias+res->C | 3 bias->planes
//      4 bias-> per-head transposed V planes [(b*32+h)*32+d][512]
template <int EPI>
__global__ __launch_bounds__(256, 2) void gemm_mfma(
    const ushort* __restrict__ Ah, const ushort* __restrict__ Al,
    const ushort* __restrict__ Bh, const ushort* __restrict__ Bl,
    const float* __restrict__ bias, const float* __restrict__ res,
    float* __restrict__ C, ushort* __restrict__ Oh, ushort* __restrict__ Ol,
    int M, int N, int K) {
  __shared__ __align__(16) ushort sAh[4096], sAl[4096], sBh[4096], sBl[4096];
  const int t = threadIdx.x, w = t >> 6, lane = t & 63;
  const int llo = lane & 15, lhi = lane >> 4;
  const int bm = blockIdx.y * 128, bn = blockIdx.x * 128;
  const int wm = w >> 1, wn = w & 1;

  const ushort* pAh0 = Ah + (size_t)(bm + lane) * K + w * 8;
  const ushort* pAh1 = pAh0 + (size_t)64 * K;
  const ushort* pAl0 = Al + (size_t)(bm + lane) * K + w * 8;
  const ushort* pAl1 = pAl0 + (size_t)64 * K;
  const ushort* pBh0 = Bh + (size_t)(bn + lane) * K + w * 8;
  const ushort* pBh1 = pBh0 + (size_t)64 * K;
  const ushort* pBl0 = Bl + (size_t)(bn + lane) * K + w * 8;
  const ushort* pBl1 = pBl0 + (size_t)64 * K;

  ushort* dAh = &sAh[w * 1024];
  ushort* dAl = &sAl[w * 1024];
  ushort* dBh = &sBh[w * 1024];
  ushort* dBl = &sBl[w * 1024];

  f32x4 acc[4][4] = {};

  for (int k0 = 0; k0 < K; k0 += 32) {
    __syncthreads();
    gl_lds16(pAh0 + k0, dAh);
    gl_lds16(pAh1 + k0, dAh + 512);
    gl_lds16(pAl0 + k0, dAl);
    gl_lds16(pAl1 + k0, dAl + 512);
    gl_lds16(pBh0 + k0, dBh);
    gl_lds16(pBh1 + k0, dBh + 512);
    gl_lds16(pBl0 + k0, dBl);
    gl_lds16(pBl1 + k0, dBl + 512);
    __syncthreads();

    bf16x8 ah[4], al[4], bh[4], bl[4];
#pragma unroll
    for (int f = 0; f < 4; ++f) {
      const int ar = (wm * 64 + f * 16 + llo) * 8;
      const int br = (wn * 64 + f * 16 + llo) * 8;
      ah[f] = *(const bf16x8*)&sAh[lhi * 1024 + ar];
      al[f] = *(const bf16x8*)&sAl[lhi * 1024 + ar];
      bh[f] = *(const bf16x8*)&sBh[lhi * 1024 + br];
      bl[f] = *(const bf16x8*)&sBl[lhi * 1024 + br];
    }
#pragma unroll
    for (int fm = 0; fm < 4; ++fm)
#pragma unroll
      for (int fn = 0; fn < 4; ++fn) {
        acc[fm][fn] = mfma32(ah[fm], bh[fn], acc[fm][fn]);
        acc[fm][fn] = mfma32(al[fm], bh[fn], acc[fm][fn]);
        acc[fm][fn] = mfma32(ah[fm], bl[fn], acc[fm][fn]);
      }
  }

#pragma unroll
  for (int fm = 0; fm < 4; ++fm) {
#pragma unroll
    for (int fn = 0; fn < 4; ++fn) {
      const int col = bn + wn * 64 + fn * 16 + llo;
      const float bc = bias[col];
      const int row0 = bm + wm * 64 + fm * 16 + lhi * 4;
      if (EPI == 4) {
        ushort4 vh, vl;
#pragma unroll
        for (int r = 0; r < 4; ++r) {
          const float v = acc[fm][fn][r] + bc;
          const ushort hh = f2bf(v);
          ((ushort*)&vh)[r] = hh;
          ((ushort*)&vl)[r] = f2bf(v - bf2f(hh));
        }
        const size_t o =
            ((size_t)(((row0 >> 9) * 32 + (col >> 5)) * 32 + (col & 31))) * 512 +
            (row0 & 511);
        *(ushort4*)(Oh + o) = vh;
        *(ushort4*)(Ol + o) = vl;
      } else {
#pragma unroll
        for (int r = 0; r < 4; ++r) {
          const size_t o = (size_t)(row0 + r) * N + col;
          float v = acc[fm][fn][r] + bc;
          if (EPI == 2) v += res[o];
          if (EPI == 1) v = 0.5f * v * (1.f + erff(v * 0.70710678118654752f));
          if (EPI == 0 || EPI == 2) {
            C[o] = v;
          } else {
            const ushort hh = f2bf(v);
            Oh[o] = hh;
            Ol[o] = f2bf(v - bf2f(hh));
          }
        }
      }
    }
  }
}

// ---------- MFMA flash attention per (b,h): 512 threads, 8 waves ----------
// Swapped QK^T (S^T = K.Q^T) so softmax is per-lane-column; split-bf16 3-pass
// for both QK^T and PV. K slab [oct4][512][8]; V^T slab [koct64][32][8].
__global__ __launch_bounds__(512, 1) void attn_mfma(
    const ushort* __restrict__ Qh, const ushort* __restrict__ Ql,
    const ushort* __restrict__ Kh, const ushort* __restrict__ Kl,
    const ushort* __restrict__ Vh, const ushort* __restrict__ Vl,
    const float* __restrict__ mask, const float* __restrict__ rel_l,
    ushort* __restrict__ Ch, ushort* __restrict__ Cl) {
  __shared__ __align__(16) ushort sKh[16384], sKl[16384];
  __shared__ __align__(16) ushort sVh[16384], sVl[16384];
  __shared__ __align__(16) ushort sPh[5120], sPl[5120];
  __shared__ float rel_s[1024];
  __shared__ float madd[512];

  const int h = blockIdx.x, b = blockIdx.y;
  const int t = threadIdx.x, w = t >> 6, lane = t & 63;
  const int llo = lane & 15, lhi = lane >> 4;
  const float SCALE = 0.17677669529663687f;  // 1/sqrt(32)

  // stage K hi/lo
#pragma unroll
  for (int it = 0; it < 4; ++it) {
    const int task = t + it * 512;  // 0..2047
    const int s = task >> 2, oct = task & 3;
    const size_t g = (size_t)(b * 512 + s) * 1024 + h * 32 + oct * 8;
    const int d = oct * 4096 + s * 8;
    *(uint4*)&sKh[d] = *(const uint4*)(Kh + g);
    *(uint4*)&sKl[d] = *(const uint4*)(Kl + g);
  }
  // stage V^T hi/lo
#pragma unroll
  for (int it = 0; it < 4; ++it) {
    const int task = t + it * 512;  // 0..2047
    const int d = task >> 6, ko = task & 63;
    const size_t g = (size_t)((b * 32 + h) * 32 + d) * 512 + ko * 8;
    const int dd = ko * 256 + d * 8;
    *(uint4*)&sVh[dd] = *(const uint4*)(Vh + g);
    *(uint4*)&sVl[dd] = *(const uint4*)(Vl + g);
  }
  for (int i = t; i < 1023; i += 512) rel_s[i] = rel_l[(size_t)i * 32 + h];
  for (int i = t; i < 512; i += 512) madd[i] = (1.f - mask[b * 512 + i]) * -1e9f;
  __syncthreads();

  uint* wPh = (uint*)(sPh + w * 640 + llo * 40);
  uint* wPl = (uint*)(sPl + w * 640 + llo * 40);
  const ushort* rP_h = sPh + w * 640 + llo * 40;
  const ushort* rP_l = sPl + w * 640 + llo * 40;

  for (int qt = 0; qt < 4; ++qt) {
    const int q = w * 64 + qt * 16 + llo;  // this lane's q-row (as MFMA col)
    const size_t qg = (size_t)(b * 512 + q) * 1024 + h * 32 + lhi * 8;
    const bf16x8 fQh = *(const bf16x8*)(Qh + qg);
    const bf16x8 fQl = *(const bf16x8*)(Ql + qg);
    float m = -INFINITY, l = 0.f;
    f32x4 acc0 = {0.f, 0.f, 0.f, 0.f};
    f32x4 acc1 = {0.f, 0.f, 0.f, 0.f};

    for (int kt2 = 0; kt2 < 16; ++kt2) {
      float p[8];
      float tm = -INFINITY;
#pragma unroll
      for (int sub = 0; sub < 2; ++sub) {
        const int kt = kt2 * 2 + sub;
        const int kr = (kt * 16 + llo) * 8;
        const bf16x8 fKh = *(const bf16x8*)&sKh[lhi * 4096 + kr];
        const bf16x8 fKl = *(const bf16x8*)&sKl[lhi * 4096 + kr];
        f32x4 s4 = {0.f, 0.f, 0.f, 0.f};
        s4 = mfma32(fKh, fQh, s4);
        s4 = mfma32(fKl, fQh, s4);
        s4 = mfma32(fKh, fQl, s4);
#pragma unroll
        for (int r = 0; r < 4; ++r) {
          const int k = kt * 16 + lhi * 4 + r;
          const float sv = (s4[r] + rel_s[q - k + 511]) * SCALE + madd[k];
          p[sub * 4 + r] = sv;
          tm = fmaxf(tm, sv);
        }
      }
      tm = fmaxf(tm, __shfl_xor(tm, 16));
      tm = fmaxf(tm, __shfl_xor(tm, 32));
      const float nm = fmaxf(m, tm);
      const float sc = __expf(m - nm);
      float ts = 0.f;
#pragma unroll
      for (int i = 0; i < 8; ++i) {
        p[i] = __expf(p[i] - nm);
        ts += p[i];
      }
      ts += __shfl_xor(ts, 16);
      ts += __shfl_xor(ts, 32);
      l = l * sc + ts;
      m = nm;
      acc0 *= sc;
      acc1 *= sc;
      // pack P (hi & residual-lo) into wave-private LDS, B-frag layout
#pragma unroll
      for (int sub = 0; sub < 2; ++sub) {
        const ushort h0 = f2bf(p[sub * 4 + 0]), h1 = f2bf(p[sub * 4 + 1]);
        const ushort h2 = f2bf(p[sub * 4 + 2]), h3 = f2bf(p[sub * 4 + 3]);
        wPh[sub * 8 + lhi * 2 + 0] = (uint)h0 | ((uint)h1 << 16);
        wPh[sub * 8 + lhi * 2 + 1] = (uint)h2 | ((uint)h3 << 16);
        const ushort g0 = f2bf(p[sub * 4 + 0] - bf2f(h0));
        const ushort g1 = f2bf(p[sub * 4 + 1] - bf2f(h1));
        const ushort g2 = f2bf(p[sub * 4 + 2] - bf2f(h2));
        const ushort g3 = f2bf(p[sub * 4 + 3] - bf2f(h3));
        wPl[sub * 8 + lhi * 2 + 0] = (uint)g0 | ((uint)g1 << 16);
        wPl[sub * 8 + lhi * 2 + 1] = (uint)g2 | ((uint)g3 << 16);
      }
      const bf16x8 fPh = *(const bf16x8*)(rP_h + lhi * 8);
      const bf16x8 fPl = *(const bf16x8*)(rP_l + lhi * 8);
      const int vb = (kt2 * 4 + lhi) * 256;
      const bf16x8 fV0h = *(const bf16x8*)&sVh[vb + llo * 8];
      const bf16x8 fV0l = *(const bf16x8*)&sVl[vb + llo * 8];
      const bf16x8 fV1h = *(const bf16x8*)&sVh[vb + (16 + llo) * 8];
      const bf16x8 fV1l = *(const bf16x8*)&sVl[vb + (16 + llo) * 8];
      acc0 = mfma32(fV0h, fPh, acc0);
      acc0 = mfma32(fV0l, fPh, acc0);
      acc0 = mfma32(fV0h, fPl, acc0);
      acc1 = mfma32(fV1h, fPh, acc1);
      acc1 = mfma32(fV1l, fPh, acc1);
      acc1 = mfma32(fV1h, fPl, acc1);
    }

    const float invl = 1.f / l;
    const size_t ob = (size_t)(b * 512 + q) * 1024 + h * 32;
    ushort4 oh, ol;
#pragma unroll
    for (int r = 0; r < 4; ++r) {
      const float c = acc0[r] * invl;
      const ushort hh = f2bf(c);
      ((ushort*)&oh)[r] = hh;
      ((ushort*)&ol)[r] = f2bf(c - bf2f(hh));
    }
    *(ushort4*)(Ch + ob + lhi * 4) = oh;
    *(ushort4*)(Cl + ob + lhi * 4) = ol;
#pragma unroll
    for (int r = 0; r < 4; ++r) {
      const float c = acc1[r] * invl;
      const ushort hh = f2bf(c);
      ((ushort*)&oh)[r] = hh;
      ((ushort*)&ol)[r] = f2bf(c - bf2f(hh));
    }
    *(ushort4*)(Ch + ob + 16 + lhi * 4) = oh;
    *(ushort4*)(Cl + ob + 16 + lhi * 4) = ol;
  }
}

// ---------- LayerNorm over rows of 1024 (+optional bf16 hi/lo planes) -------
__global__ __launch_bounds__(256) void ln_kernel(
    const float* __restrict__ X, const float* __restrict__ g,
    const float* __restrict__ bt, float* __restrict__ out,
    ushort* __restrict__ Oh, ushort* __restrict__ Ol) {
  __shared__ float sb[4];
  const int row = blockIdx.x, t = threadIdx.x;
  const float4 x = *(const float4*)&X[(size_t)row * 1024 + t * 4];
  const float s = block_reduce_sum(x.x + x.y + x.z + x.w, sb);
  const float mu = s * (1.f / 1024.f);
  const float dx = x.x - mu, dy = x.y - mu, dz = x.z - mu, dw = x.w - mu;
  const float ss = block_reduce_sum(dx * dx + dy * dy + dz * dz + dw * dw, sb);
  const float rs = rsqrtf(ss * (1.f / 1024.f) + 1e-12f);
  const float4 gv = *(const float4*)&g[t * 4];
  const float4 bv = *(const float4*)&bt[t * 4];
  float4 o;
  o.x = dx * rs * gv.x + bv.x;
  o.y = dy * rs * gv.y + bv.y;
  o.z = dz * rs * gv.z + bv.z;
  o.w = dw * rs * gv.w + bv.w;
  *(float4*)&out[(size_t)row * 1024 + t * 4] = o;
  if (Oh) {
    ushort4 vh, vl;
    vh.x = f2bf(o.x); vl.x = f2bf(o.x - bf2f(vh.x));
    vh.y = f2bf(o.y); vl.y = f2bf(o.y - bf2f(vh.y));
    vh.z = f2bf(o.z); vl.z = f2bf(o.z - bf2f(vh.z));
    vh.w = f2bf(o.w); vl.w = f2bf(o.w - bf2f(vh.w));
    *(ushort4*)&Oh[(size_t)row * 1024 + t * 4] = vh;
    *(ushort4*)&Ol[(size_t)row * 1024 + t * 4] = vl;
  }
}

// ---------- pooling: mean + max + first token ----------
__global__ __launch_bounds__(128) void pool_kernel(
    const float* __restrict__ X, const float* __restrict__ mask,
    float* __restrict__ pooled) {
  const int b = blockIdx.y;
  const int col = blockIdx.x * 128 + threadIdx.x;
  float sum = 0.f, mx = -INFINITY, cnt = 0.f;
  for (int s = 0; s < 512; ++s) {
    const float v = X[(size_t)(b * 512 + s) * 1024 + col];
    const float mk = mask[b * 512 + s];
    sum = fmaf(v, mk, sum);
    cnt += mk;
    mx = fmaxf(mx, v + (1.f - mk) * -1e9f);
  }
  pooled[(size_t)b * 3072 + col] = sum / cnt;
  pooled[(size_t)b * 3072 + 1024 + col] = mx;
  pooled[(size_t)b * 3072 + 2048 + col] = X[(size_t)(b * 512) * 1024 + col];
}

// ---------- small pooled GEMM [8,3072]@[3072,1024] ----------
__global__ __launch_bounds__(256) void pool_gemm_kernel(
    const float* __restrict__ P, const float* __restrict__ W,
    const float* __restrict__ bias, float* __restrict__ out) {
  const int idx = blockIdx.x * 256 + threadIdx.x;
  const int b = idx >> 10, n = idx & 1023;
  const float* pr = P + (size_t)b * 3072;
  float a = 0.f;
  for (int k = 0; k < 3072; ++k) a = fmaf(pr[k], W[(size_t)k * 1024 + n], a);
  out[idx] = a + bias[n];
}

// ---------- classifier [8,1024]@[1024,20] ----------
__global__ __launch_bounds__(64) void cls_kernel(
    const float* __restrict__ X, const float* __restrict__ W,
    const float* __restrict__ bias, float* __restrict__ out) {
  const int b = blockIdx.x, n = threadIdx.x;
  if (n < 20) {
    float a = 0.f;
    for (int k = 0; k < 1024; ++k)
      a = fmaf(X[(size_t)b * 1024 + k], W[(size_t)k * 20 + n], a);
    out[b * 20 + n] = a + bias[n];
  }
}

extern "C" void kernel_launch(void* const* d_in, const int* in_sizes, int n_in,
                              void* d_out, int out_size, void* d_ws, size_t ws_size,
                              hipStream_t stream) {
  const float* hs    = (const float*)d_in[0];
  const float* amask = (const float*)d_in[1];
  const float* Wq    = (const float*)d_in[2];
  const float* bq    = (const float*)d_in[3];
  const float* Wk    = (const float*)d_in[4];
  const float* bk    = (const float*)d_in[5];
  const float* Wv    = (const float*)d_in[6];
  const float* bv    = (const float*)d_in[7];
  const float* Wo    = (const float*)d_in[8];
  const float* bo    = (const float*)d_in[9];
  const float* ln1g  = (const float*)d_in[10];
  const float* ln1b  = (const float*)d_in[11];
  const float* W1    = (const float*)d_in[12];
  const float* b1    = (const float*)d_in[13];
  const float* W2    = (const float*)d_in[14];
  const float* b2    = (const float*)d_in[15];
  const float* ln2g  = (const float*)d_in[16];
  const float* ln2b  = (const float*)d_in[17];
  const float* rel   = (const float*)d_in[18];
  const float* poolW = (const float*)d_in[19];
  const float* poolb = (const float*)d_in[20];
  const float* plng  = (const float*)d_in[21];
  const float* plnb  = (const float*)d_in[22];
  const float* clsW  = (const float*)d_in[23];
  const float* clsb  = (const float*)d_in[24];

  char* W = (char*)d_ws;
  const size_t MB = (size_t)1 << 20;
  float* buf_t  = (float*)(W + 0 * MB);    // 16MB fp32
  float* buf_h1 = (float*)(W + 16 * MB);   // 16MB fp32
  float* buf_x  = (float*)(W + 32 * MB);   // 16MB fp32
  ushort* Qph  = (ushort*)(W + 48 * MB);   // 8MB each plane
  ushort* Qpl  = (ushort*)(W + 56 * MB);
  ushort* Kph  = (ushort*)(W + 64 * MB);
  ushort* Kpl  = (ushort*)(W + 72 * MB);
  ushort* VTh  = (ushort*)(W + 80 * MB);
  ushort* VTl  = (ushort*)(W + 88 * MB);
  ushort* CTXh = (ushort*)(W + 96 * MB);   // also X planes (phase-disjoint)
  ushort* CTXl = (ushort*)(W + 104 * MB);
  ushort* Xh = CTXh;
  ushort* Xl = CTXl;
  ushort* F1h = (ushort*)(W + 48 * MB);    // 32MB, aliases Q..K (dead by FFN1)
  ushort* F1l = (ushort*)(W + 80 * MB);    // 32MB, aliases VT..CTX
  ushort* H1h = (ushort*)(W + 112 * MB);
  ushort* H1l = (ushort*)(W + 120 * MB);
  ushort* Wth = (ushort*)(W + 128 * MB);
  ushort* Wtl = (ushort*)(W + 136 * MB);
  float* pooled  = (float*)(W + 128 * MB);  // aliases Wt (dead at pooling)
  float* pool_h  = pooled + 8 * 3072;
  float* pool_h2 = pool_h + 8 * 1024;

  const int n4act = (4096 * 1024) / 4;
  const dim3 gP(1024 / 128, 4096 / 128);
  const dim3 gF1(4096 / 128, 4096 / 128);
  const dim3 wsQ(1024 / 32, 1024 / 32);

  asplit<<<n4act / 256, 256, 0, stream>>>(hs, Xh, Xl, n4act);

  const float* x_in = hs;
  for (int l = 0; l < 4; ++l) {
    const float* Wq_l = Wq + (size_t)l * 1024 * 1024;
    const float* Wk_l = Wk + (size_t)l * 1024 * 1024;
    const float* Wv_l = Wv + (size_t)l * 1024 * 1024;
    const float* Wo_l = Wo + (size_t)l * 1024 * 1024;
    const float* W1_l = W1 + (size_t)l * 1024 * 4096;
    const float* W2_l = W2 + (size_t)l * 4096 * 1024;

    wsplit_t<<<wsQ, 256, 0, stream>>>(Wq_l, Wth, Wtl, 1024, 1024);
    gemm_mfma<3><<<gP, 256, 0, stream>>>(Xh, Xl, Wth, Wtl, bq + l * 1024,
        nullptr, nullptr, Qph, Qpl, 4096, 1024, 1024);
    wsplit_t<<<wsQ, 256, 0, stream>>>(Wk_l, Wth, Wtl, 1024, 1024);
    gemm_mfma<3><<<gP, 256, 0, stream>>>(Xh, Xl, Wth, Wtl, bk + l * 1024,
        nullptr, nullptr, Kph, Kpl, 4096, 1024, 1024);
    wsplit_t<<<wsQ, 256, 0, stream>>>(Wv_l, Wth, Wtl, 1024, 1024);
    gemm_mfma<4><<<gP, 256, 0, stream>>>(Xh, Xl, Wth, Wtl, bv + l * 1024,
        nullptr, nullptr, VTh, VTl, 4096, 1024, 1024);

    attn_mfma<<<dim3(32, 8), 512, 0, stream>>>(Qph, Qpl, Kph, Kpl, VTh, VTl,
        amask, rel + (size_t)l * 1023 * 32, CTXh, CTXl);

    wsplit_t<<<wsQ, 256, 0, stream>>>(Wo_l, Wth, Wtl, 1024, 1024);
    gemm_mfma<2><<<gP, 256, 0, stream>>>(CTXh, CTXl, Wth, Wtl, bo + l * 1024,
        x_in, buf_t, nullptr, nullptr, 4096, 1024, 1024);
    ln_kernel<<<4096, 256, 0, stream>>>(buf_t, ln1g + l * 1024, ln1b + l * 1024,
                                        buf_h1, H1h, H1l);

    wsplit_t<<<dim3(4096 / 32, 1024 / 32), 256, 0, stream>>>(W1_l, Wth, Wtl, 1024, 4096);
    gemm_mfma<1><<<gF1, 256, 0, stream>>>(H1h, H1l, Wth, Wtl, b1 + l * 4096,
        nullptr, nullptr, F1h, F1l, 4096, 4096, 1024);
    wsplit_t<<<dim3(1024 / 32, 4096 / 32), 256, 0, stream>>>(W2_l, Wth, Wtl, 4096, 1024);
    gemm_mfma<2><<<gP, 256, 0, stream>>>(F1h, F1l, Wth, Wtl, b2 + l * 1024,
        buf_h1, buf_t, nullptr, nullptr, 4096, 1024, 4096);
    ln_kernel<<<4096, 256, 0, stream>>>(buf_t, ln2g + l * 1024, ln2b + l * 1024,
                                        buf_x, Xh, Xl);
    x_in = buf_x;
  }

  pool_kernel<<<dim3(8, 8), 128, 0, stream>>>(buf_x, amask, pooled);
  pool_gemm_kernel<<<32, 256, 0, stream>>>(pooled, poolW, poolb, pool_h);
  ln_kernel<<<8, 256, 0, stream>>>(pool_h, plng, plnb, pool_h2, nullptr, nullptr);
  cls_kernel<<<8, 64, 0, stream>>>(pool_h2, clsW, clsb, (float*)d_out);
}

// Round 5
// 2739.226 us; speedup vs baseline: 2.7542x; 1.1970x over previous
//
#include <hip/hip_runtime.h>
#include <math.h>

typedef __attribute__((ext_vector_type(8))) short bf16x8;
typedef __attribute__((ext_vector_type(4))) float f32x4;

// ---------- bf16 helpers (RNE) ----------
__device__ __forceinline__ ushort f2bf(float x) {
  unsigned u = __float_as_uint(x);
  return (ushort)((u + 0x7FFFu + ((u >> 16) & 1u)) >> 16);
}
__device__ __forceinline__ float bf2f(ushort h) {
  return __uint_as_float(((unsigned)h) << 16);
}
__device__ __forceinline__ void gl_lds16(const ushort* g, ushort* l) {
  __builtin_amdgcn_global_load_lds(
      (const __attribute__((address_space(1))) unsigned int*)g,
      (__attribute__((address_space(3))) unsigned int*)l, 16, 0, 0);
}
__device__ __forceinline__ f32x4 mfma32(bf16x8 a, bf16x8 b, f32x4 c) {
  return __builtin_amdgcn_mfma_f32_16x16x32_bf16(a, b, c, 0, 0, 0);
}

// ---------- block-wide sum reduce (256 threads = 4 waves) ----------
__device__ __forceinline__ float block_reduce_sum(float v, float* sb) {
#pragma unroll
  for (int o = 32; o > 0; o >>= 1) v += __shfl_down(v, o, 64);
  const int t = threadIdx.x;
  if ((t & 63) == 0) sb[t >> 6] = v;
  __syncthreads();
  v = sb[0] + sb[1] + sb[2] + sb[3];
  __syncthreads();
  return v;
}

// ---------- activation split: fp32 -> (hi, lo) bf16 planes ----------
__global__ __launch_bounds__(256) void asplit(const float* __restrict__ X,
                                              ushort* __restrict__ H,
                                              ushort* __restrict__ L, int n4) {
  const int i = blockIdx.x * 256 + threadIdx.x;
  if (i >= n4) return;
  const float4 x = ((const float4*)X)[i];
  ushort4 h, l;
  h.x = f2bf(x.x); l.x = f2bf(x.x - bf2f(h.x));
  h.y = f2bf(x.y); l.y = f2bf(x.y - bf2f(h.y));
  h.z = f2bf(x.z); l.z = f2bf(x.z - bf2f(h.z));
  h.w = f2bf(x.w); l.w = f2bf(x.w - bf2f(h.w));
  ((ushort4*)H)[i] = h;
  ((ushort4*)L)[i] = l;
}

// ---------- bias concat for fused QKV ----------
__global__ __launch_bounds__(256) void concat3(const float* __restrict__ a,
                                               const float* __restrict__ b,
                                               const float* __restrict__ c,
                                               float* __restrict__ o) {
  const int i = blockIdx.x * 256 + threadIdx.x;  // 0..3071
  o[i] = i < 1024 ? a[i] : (i < 2048 ? b[i - 1024] : c[i - 2048]);
}

// ---------- weight transpose+split: W[K,N] fp32 -> Th,Tl [N,K] bf16 ----------
__global__ __launch_bounds__(256) void wsplit_t(const float* __restrict__ W,
                                                ushort* __restrict__ Th,
                                                ushort* __restrict__ Tl,
                                                int K, int N) {
  __shared__ float s[32][33];
  const int tx = threadIdx.x & 31, ty = threadIdx.x >> 5;
  const int n0 = blockIdx.x * 32, k0 = blockIdx.y * 32;
#pragma unroll
  for (int i = 0; i < 4; ++i)
    s[ty + i * 8][tx] = W[(size_t)(k0 + ty + i * 8) * N + n0 + tx];
  __syncthreads();
#pragma unroll
  for (int i = 0; i < 4; ++i) {
    const int n = ty + i * 8;
    const float x = s[tx][n];
    const ushort h = f2bf(x);
    const size_t o = (size_t)(n0 + n) * K + k0 + tx;
    Th[o] = h;
    Tl[o] = f2bf(x - bf2f(h));
  }
}

// ---------- split-bf16 MFMA GEMM, 128 x (NF*32) tile, BK=32, dbuf 2-phase ----
// NF = per-wave N fragments (2 -> BN=64, 4 -> BN=128). 4 waves as 2x2.
// EPI: 1 bias+GELU->planes | 2 bias+res->C |
//      5 QKV fused: col<2048 -> Q/K planes [2][4096][1024]; col>=2048 ->
//        transposed V planes at Oh+8M: [(b*32+h)*32+d][512]
template <int EPI, int NF>
__global__ __launch_bounds__(256, NF == 4 ? 2 : 3) void gemm_mfma(
    const ushort* __restrict__ Ah, const ushort* __restrict__ Al,
    const ushort* __restrict__ Bh, const ushort* __restrict__ Bl,
    const float* __restrict__ bias, const float* __restrict__ res,
    float* __restrict__ C, ushort* __restrict__ Oh, ushort* __restrict__ Ol,
    int M, int N, int K) {
  constexpr int BSZ = NF * 32 * 32;  // B tile ushorts
  __shared__ __align__(16) ushort sAh[2][4096], sAl[2][4096];
  __shared__ __align__(16) ushort sBh[2][BSZ], sBl[2][BSZ];
  const int t = threadIdx.x, w = t >> 6, lane = t & 63;
  const int llo = lane & 15, lhi = lane >> 4;
  const int wm = w >> 1, wn = w & 1;

  // XCD-aware bijective swizzle (all our grids have nwg % 8 == 0)
  const int gx = gridDim.x;
  int wg = blockIdx.y * gx + blockIdx.x;
  const int nwg = gx * gridDim.y;
  wg = (wg & 7) * (nwg >> 3) + (wg >> 3);
  const int bm = (wg / gx) * 128, bn = (wg % gx) * (NF * 32);

  const ushort* pAh0 = Ah + (size_t)(bm + lane) * K + w * 8;
  const ushort* pAh1 = pAh0 + (size_t)64 * K;
  const ushort* pAl0 = Al + (size_t)(bm + lane) * K + w * 8;
  const ushort* pAl1 = pAl0 + (size_t)64 * K;
  const ushort* pBh0 = Bh + (size_t)(bn + lane) * K + w * 8;
  const ushort* pBl0 = Bl + (size_t)(bn + lane) * K + w * 8;
  const ushort* pBh1 = (NF == 4) ? pBh0 + (size_t)64 * K : pBh0;
  const ushort* pBl1 = (NF == 4) ? pBl0 + (size_t)64 * K : pBl0;

  auto STAGE = [&](int buf, int k0) {
    gl_lds16(pAh0 + k0, &sAh[buf][w * 1024]);
    gl_lds16(pAh1 + k0, &sAh[buf][w * 1024 + 512]);
    gl_lds16(pAl0 + k0, &sAl[buf][w * 1024]);
    gl_lds16(pAl1 + k0, &sAl[buf][w * 1024 + 512]);
    if (NF == 4) {
      gl_lds16(pBh0 + k0, &sBh[buf][w * 1024]);
      gl_lds16(pBh1 + k0, &sBh[buf][w * 1024 + 512]);
      gl_lds16(pBl0 + k0, &sBl[buf][w * 1024]);
      gl_lds16(pBl1 + k0, &sBl[buf][w * 1024 + 512]);
    } else {
      gl_lds16(pBh0 + k0, &sBh[buf][w * 512]);
      gl_lds16(pBl0 + k0, &sBl[buf][w * 512]);
    }
  };

  f32x4 acc[4][NF] = {};
  const int NT = K >> 5;
  STAGE(0, 0);
  __syncthreads();  // vmcnt(0) drain + barrier: tile 0 ready
  int cur = 0;
  for (int kt = 0; kt < NT; ++kt) {
    if (kt + 1 < NT) STAGE(cur ^ 1, (kt + 1) << 5);  // prefetch next tile
    bf16x8 ah[4], al[4], bh[NF], bl[NF];
#pragma unroll
    for (int f = 0; f < 4; ++f) {
      const int ar = (wm * 64 + f * 16 + llo) * 8;
      ah[f] = *(const bf16x8*)&sAh[cur][lhi * 1024 + ar];
      al[f] = *(const bf16x8*)&sAl[cur][lhi * 1024 + ar];
    }
#pragma unroll
    for (int f = 0; f < NF; ++f) {
      const int br = (wn * (NF * 16) + f * 16 + llo) * 8;
      bh[f] = *(const bf16x8*)&sBh[cur][lhi * (NF * 256) + br];
      bl[f] = *(const bf16x8*)&sBl[cur][lhi * (NF * 256) + br];
    }
#pragma unroll
    for (int fm = 0; fm < 4; ++fm)
#pragma unroll
      for (int fn = 0; fn < NF; ++fn) {
        acc[fm][fn] = mfma32(ah[fm], bh[fn], acc[fm][fn]);
        acc[fm][fn] = mfma32(al[fm], bh[fn], acc[fm][fn]);
        acc[fm][fn] = mfma32(ah[fm], bl[fn], acc[fm][fn]);
      }
    __syncthreads();  // vmcnt(0): prefetch complete (AFTER compute) + barrier
    cur ^= 1;
  }

  // epilogue: C/D map col = lane&15, row = (lane>>4)*4 + r
#pragma unroll
  for (int fm = 0; fm < 4; ++fm) {
    const int row0 = bm + wm * 64 + fm * 16 + lhi * 4;
#pragma unroll
    for (int fn = 0; fn < NF; ++fn) {
      const int col = bn + wn * (NF * 16) + fn * 16 + llo;
      const float bc = bias[col];
      if (EPI == 5) {
        if (col < 2048) {
          const size_t base = (size_t)(col >> 10) * (4096 * 1024) + (col & 1023);
#pragma unroll
          for (int r = 0; r < 4; ++r) {
            const float v = acc[fm][fn][r] + bc;
            const ushort hh = f2bf(v);
            Oh[base + (size_t)(row0 + r) * 1024] = hh;
            Ol[base + (size_t)(row0 + r) * 1024] = f2bf(v - bf2f(hh));
          }
        } else {
          const int c = col - 2048;
          ushort4 vh, vl;
#pragma unroll
          for (int r = 0; r < 4; ++r) {
            const float v = acc[fm][fn][r] + bc;
            const ushort hh = f2bf(v);
            ((ushort*)&vh)[r] = hh;
            ((ushort*)&vl)[r] = f2bf(v - bf2f(hh));
          }
          const size_t o = (size_t)8 * 1024 * 1024 +
              ((size_t)(((row0 >> 9) * 32 + (c >> 5)) * 32 + (c & 31))) * 512 +
              (row0 & 511);
          *(ushort4*)(Oh + o) = vh;
          *(ushort4*)(Ol + o) = vl;
        }
      } else {
#pragma unroll
        for (int r = 0; r < 4; ++r) {
          const size_t o = (size_t)(row0 + r) * N + col;
          float v = acc[fm][fn][r] + bc;
          if (EPI == 2) {
            v += res[o];
            C[o] = v;
          } else {  // EPI == 1: GELU -> planes
            v = 0.5f * v * (1.f + erff(v * 0.70710678118654752f));
            const ushort hh = f2bf(v);
            Oh[o] = hh;
            Ol[o] = f2bf(v - bf2f(hh));
          }
        }
      }
    }
  }
}

// ---------- MFMA flash attention per (b,h): 512 threads, 8 waves ----------
__global__ __launch_bounds__(512, 1) void attn_mfma(
    const ushort* __restrict__ Qh, const ushort* __restrict__ Ql,
    const ushort* __restrict__ Kh, const ushort* __restrict__ Kl,
    const ushort* __restrict__ Vh, const ushort* __restrict__ Vl,
    const float* __restrict__ mask, const float* __restrict__ rel_l,
    ushort* __restrict__ Ch, ushort* __restrict__ Cl) {
  __shared__ __align__(16) ushort sKh[16384], sKl[16384];
  __shared__ __align__(16) ushort sVh[16384], sVl[16384];
  __shared__ __align__(16) ushort sPh[5120], sPl[5120];
  __shared__ float rel_s[1024];
  __shared__ float madd[512];

  const int h = blockIdx.x, b = blockIdx.y;
  const int t = threadIdx.x, w = t >> 6, lane = t & 63;
  const int llo = lane & 15, lhi = lane >> 4;
  const float SCALE = 0.17677669529663687f;  // 1/sqrt(32)

#pragma unroll
  for (int it = 0; it < 4; ++it) {
    const int task = t + it * 512;
    const int s = task >> 2, oct = task & 3;
    const size_t g = (size_t)(b * 512 + s) * 1024 + h * 32 + oct * 8;
    const int d = oct * 4096 + s * 8;
    *(uint4*)&sKh[d] = *(const uint4*)(Kh + g);
    *(uint4*)&sKl[d] = *(const uint4*)(Kl + g);
  }
#pragma unroll
  for (int it = 0; it < 4; ++it) {
    const int task = t + it * 512;
    const int d = task >> 6, ko = task & 63;
    const size_t g = (size_t)((b * 32 + h) * 32 + d) * 512 + ko * 8;
    const int dd = ko * 256 + d * 8;
    *(uint4*)&sVh[dd] = *(const uint4*)(Vh + g);
    *(uint4*)&sVl[dd] = *(const uint4*)(Vl + g);
  }
  for (int i = t; i < 1023; i += 512) rel_s[i] = rel_l[(size_t)i * 32 + h];
  for (int i = t; i < 512; i += 512) madd[i] = (1.f - mask[b * 512 + i]) * -1e9f;
  __syncthreads();

  uint* wPh = (uint*)(sPh + w * 640 + llo * 40);
  uint* wPl = (uint*)(sPl + w * 640 + llo * 40);
  const ushort* rP_h = sPh + w * 640 + llo * 40;
  const ushort* rP_l = sPl + w * 640 + llo * 40;

  for (int qt = 0; qt < 4; ++qt) {
    const int q = w * 64 + qt * 16 + llo;
    const size_t qg = (size_t)(b * 512 + q) * 1024 + h * 32 + lhi * 8;
    const bf16x8 fQh = *(const bf16x8*)(Qh + qg);
    const bf16x8 fQl = *(const bf16x8*)(Ql + qg);
    float m = -INFINITY, l = 0.f;
    f32x4 acc0 = {0.f, 0.f, 0.f, 0.f};
    f32x4 acc1 = {0.f, 0.f, 0.f, 0.f};

    for (int kt2 = 0; kt2 < 16; ++kt2) {
      float p[8];
      float tm = -INFINITY;
#pragma unroll
      for (int sub = 0; sub < 2; ++sub) {
        const int kt = kt2 * 2 + sub;
        const int kr = (kt * 16 + llo) * 8;
        const bf16x8 fKh = *(const bf16x8*)&sKh[lhi * 4096 + kr];
        const bf16x8 fKl = *(const bf16x8*)&sKl[lhi * 4096 + kr];
        f32x4 s4 = {0.f, 0.f, 0.f, 0.f};
        s4 = mfma32(fKh, fQh, s4);
        s4 = mfma32(fKl, fQh, s4);
        s4 = mfma32(fKh, fQl, s4);
#pragma unroll
        for (int r = 0; r < 4; ++r) {
          const int k = kt * 16 + lhi * 4 + r;
          const float sv = (s4[r] + rel_s[q - k + 511]) * SCALE + madd[k];
          p[sub * 4 + r] = sv;
          tm = fmaxf(tm, sv);
        }
      }
      tm = fmaxf(tm, __shfl_xor(tm, 16));
      tm = fmaxf(tm, __shfl_xor(tm, 32));
      const float nm = fmaxf(m, tm);
      const float sc = __expf(m - nm);
      float ts = 0.f;
#pragma unroll
      for (int i = 0; i < 8; ++i) {
        p[i] = __expf(p[i] - nm);
        ts += p[i];
      }
      ts += __shfl_xor(ts, 16);
      ts += __shfl_xor(ts, 32);
      l = l * sc + ts;
      m = nm;
      acc0 *= sc;
      acc1 *= sc;
#pragma unroll
      for (int sub = 0; sub < 2; ++sub) {
        const ushort h0 = f2bf(p[sub * 4 + 0]), h1 = f2bf(p[sub * 4 + 1]);
        const ushort h2 = f2bf(p[sub * 4 + 2]), h3 = f2bf(p[sub * 4 + 3]);
        wPh[sub * 8 + lhi * 2 + 0] = (uint)h0 | ((uint)h1 << 16);
        wPh[sub * 8 + lhi * 2 + 1] = (uint)h2 | ((uint)h3 << 16);
        const ushort g0 = f2bf(p[sub * 4 + 0] - bf2f(h0));
        const ushort g1 = f2bf(p[sub * 4 + 1] - bf2f(h1));
        const ushort g2 = f2bf(p[sub * 4 + 2] - bf2f(h2));
        const ushort g3 = f2bf(p[sub * 4 + 3] - bf2f(h3));
        wPl[sub * 8 + lhi * 2 + 0] = (uint)g0 | ((uint)g1 << 16);
        wPl[sub * 8 + lhi * 2 + 1] = (uint)g2 | ((uint)g3 << 16);
      }
      const bf16x8 fPh = *(const bf16x8*)(rP_h + lhi * 8);
      const bf16x8 fPl = *(const bf16x8*)(rP_l + lhi * 8);
      const int vb = (kt2 * 4 + lhi) * 256;
      const bf16x8 fV0h = *(const bf16x8*)&sVh[vb + llo * 8];
      const bf16x8 fV0l = *(const bf16x8*)&sVl[vb + llo * 8];
      const bf16x8 fV1h = *(const bf16x8*)&sVh[vb + (16 + llo) * 8];
      const bf16x8 fV1l = *(const bf16x8*)&sVl[vb + (16 + llo) * 8];
      acc0 = mfma32(fV0h, fPh, acc0);
      acc0 = mfma32(fV0l, fPh, acc0);
      acc0 = mfma32(fV0h, fPl, acc0);
      acc1 = mfma32(fV1h, fPh, acc1);
      acc1 = mfma32(fV1l, fPh, acc1);
      acc1 = mfma32(fV1h, fPl, acc1);
    }

    const float invl = 1.f / l;
    const size_t ob = (size_t)(b * 512 + q) * 1024 + h * 32;
    ushort4 oh, ol;
#pragma unroll
    for (int r = 0; r < 4; ++r) {
      const float c = acc0[r] * invl;
      const ushort hh = f2bf(c);
      ((ushort*)&oh)[r] = hh;
      ((ushort*)&ol)[r] = f2bf(c - bf2f(hh));
    }
    *(ushort4*)(Ch + ob + lhi * 4) = oh;
    *(ushort4*)(Cl + ob + lhi * 4) = ol;
#pragma unroll
    for (int r = 0; r < 4; ++r) {
      const float c = acc1[r] * invl;
      const ushort hh = f2bf(c);
      ((ushort*)&oh)[r] = hh;
      ((ushort*)&ol)[r] = f2bf(c - bf2f(hh));
    }
    *(ushort4*)(Ch + ob + 16 + lhi * 4) = oh;
    *(ushort4*)(Cl + ob + 16 + lhi * 4) = ol;
  }
}

// ---------- LayerNorm over rows of 1024 (+optional bf16 hi/lo planes) -------
__global__ __launch_bounds__(256) void ln_kernel(
    const float* __restrict__ X, const float* __restrict__ g,
    const float* __restrict__ bt, float* __restrict__ out,
    ushort* __restrict__ Oh, ushort* __restrict__ Ol) {
  __shared__ float sb[4];
  const int row = blockIdx.x, t = threadIdx.x;
  const float4 x = *(const float4*)&X[(size_t)row * 1024 + t * 4];
  const float s = block_reduce_sum(x.x + x.y + x.z + x.w, sb);
  const float mu = s * (1.f / 1024.f);
  const float dx = x.x - mu, dy = x.y - mu, dz = x.z - mu, dw = x.w - mu;
  const float ss = block_reduce_sum(dx * dx + dy * dy + dz * dz + dw * dw, sb);
  const float rs = rsqrtf(ss * (1.f / 1024.f) + 1e-12f);
  const float4 gv = *(const float4*)&g[t * 4];
  const float4 bv = *(const float4*)&bt[t * 4];
  float4 o;
  o.x = dx * rs * gv.x + bv.x;
  o.y = dy * rs * gv.y + bv.y;
  o.z = dz * rs * gv.z + bv.z;
  o.w = dw * rs * gv.w + bv.w;
  *(float4*)&out[(size_t)row * 1024 + t * 4] = o;
  if (Oh) {
    ushort4 vh, vl;
    vh.x = f2bf(o.x); vl.x = f2bf(o.x - bf2f(vh.x));
    vh.y = f2bf(o.y); vl.y = f2bf(o.y - bf2f(vh.y));
    vh.z = f2bf(o.z); vl.z = f2bf(o.z - bf2f(vh.z));
    vh.w = f2bf(o.w); vl.w = f2bf(o.w - bf2f(vh.w));
    *(ushort4*)&Oh[(size_t)row * 1024 + t * 4] = vh;
    *(ushort4*)&Ol[(size_t)row * 1024 + t * 4] = vl;
  }
}

// ---------- pooling: mean + max + first token ----------
__global__ __launch_bounds__(128) void pool_kernel(
    const float* __restrict__ X, const float* __restrict__ mask,
    float* __restrict__ pooled) {
  const int b = blockIdx.y;
  const int col = blockIdx.x * 128 + threadIdx.x;
  float sum = 0.f, mx = -INFINITY, cnt = 0.f;
  for (int s = 0; s < 512; ++s) {
    const float v = X[(size_t)(b * 512 + s) * 1024 + col];
    const float mk = mask[b * 512 + s];
    sum = fmaf(v, mk, sum);
    cnt += mk;
    mx = fmaxf(mx, v + (1.f - mk) * -1e9f);
  }
  pooled[(size_t)b * 3072 + col] = sum / cnt;
  pooled[(size_t)b * 3072 + 1024 + col] = mx;
  pooled[(size_t)b * 3072 + 2048 + col] = X[(size_t)(b * 512) * 1024 + col];
}

// ---------- small pooled GEMM [8,3072]@[3072,1024] ----------
__global__ __launch_bounds__(256) void pool_gemm_kernel(
    const float* __restrict__ P, const float* __restrict__ W,
    const float* __restrict__ bias, float* __restrict__ out) {
  const int idx = blockIdx.x * 256 + threadIdx.x;
  const int b = idx >> 10, n = idx & 1023;
  const float* pr = P + (size_t)b * 3072;
  float a = 0.f;
  for (int k = 0; k < 3072; ++k) a = fmaf(pr[k], W[(size_t)k * 1024 + n], a);
  out[idx] = a + bias[n];
}

// ---------- classifier [8,1024]@[1024,20] ----------
__global__ __launch_bounds__(64) void cls_kernel(
    const float* __restrict__ X, const float* __restrict__ W,
    const float* __restrict__ bias, float* __restrict__ out) {
  const int b = blockIdx.x, n = threadIdx.x;
  if (n < 20) {
    float a = 0.f;
    for (int k = 0; k < 1024; ++k)
      a = fmaf(X[(size_t)b * 1024 + k], W[(size_t)k * 20 + n], a);
    out[b * 20 + n] = a + bias[n];
  }
}

extern "C" void kernel_launch(void* const* d_in, const int* in_sizes, int n_in,
                              void* d_out, int out_size, void* d_ws, size_t ws_size,
                              hipStream_t stream) {
  const float* hs    = (const float*)d_in[0];
  const float* amask = (const float*)d_in[1];
  const float* Wq    = (const float*)d_in[2];
  const float* bq    = (const float*)d_in[3];
  const float* Wk    = (const float*)d_in[4];
  const float* bk    = (const float*)d_in[5];
  const float* Wv    = (const float*)d_in[6];
  const float* bv    = (const float*)d_in[7];
  const float* Wo    = (const float*)d_in[8];
  const float* bo    = (const float*)d_in[9];
  const float* ln1g  = (const float*)d_in[10];
  const float* ln1b  = (const float*)d_in[11];
  const float* W1    = (const float*)d_in[12];
  const float* b1    = (const float*)d_in[13];
  const float* W2    = (const float*)d_in[14];
  const float* b2    = (const float*)d_in[15];
  const float* ln2g  = (const float*)d_in[16];
  const float* ln2b  = (const float*)d_in[17];
  const float* rel   = (const float*)d_in[18];
  const float* poolW = (const float*)d_in[19];
  const float* poolb = (const float*)d_in[20];
  const float* plng  = (const float*)d_in[21];
  const float* plnb  = (const float*)d_in[22];
  const float* clsW  = (const float*)d_in[23];
  const float* clsb  = (const float*)d_in[24];

  char* W = (char*)d_ws;
  const size_t MB = (size_t)1 << 20;
  const size_t QK = (size_t)4096 * 1024;  // activation plane stride (elements)
  const size_t WP = (size_t)1024 * 1024;  // weight plane stride (elements)
  float* buf_t  = (float*)(W + 0 * MB);
  float* buf_h1 = (float*)(W + 16 * MB);
  float* buf_x  = (float*)(W + 32 * MB);
  ushort* PLh = (ushort*)(W + 48 * MB);  // Q(0..4M) K(4M..8M) V^T(8M..12M), 24MB
  ushort* PLl = (ushort*)(W + 72 * MB);  // same layout, 24MB
  ushort* CTXh = (ushort*)(W + 96 * MB);  // also next-layer X planes
  ushort* CTXl = (ushort*)(W + 104 * MB);
  ushort* Xh = CTXh;
  ushort* Xl = CTXl;
  ushort* F1h = (ushort*)(W + 48 * MB);   // 32MB, aliases PL (dead by FFN1)
  ushort* F1l = (ushort*)(W + 80 * MB);   // 32MB, aliases PL-tail+CTX
  ushort* H1h = (ushort*)(W + 112 * MB);
  ushort* H1l = (ushort*)(W + 120 * MB);
  ushort* Wth = (ushort*)(W + 128 * MB);  // up to 6MB ([3072][1024])
  ushort* Wtl = (ushort*)(W + 136 * MB);
  float* bcat = (float*)(W + 144 * MB);   // 12KB
  float* pooled  = (float*)(W + 145 * MB);
  float* pool_h  = pooled + 8 * 3072;
  float* pool_h2 = pool_h + 8 * 1024;

  const int n4act = (4096 * 1024) / 4;
  const dim3 gQKV(3072 / 128, 32);  // 768 blocks
  const dim3 gN64(1024 / 64, 32);   // 512 blocks (Wo, FFN2)
  const dim3 gF1(4096 / 128, 32);   // 1024 blocks
  const dim3 wsQ(1024 / 32, 1024 / 32);

  asplit<<<n4act / 256, 256, 0, stream>>>(hs, Xh, Xl, n4act);

  const float* x_in = hs;
  for (int l = 0; l < 4; ++l) {
    const float* Wq_l = Wq + (size_t)l * 1024 * 1024;
    const float* Wk_l = Wk + (size_t)l * 1024 * 1024;
    const float* Wv_l = Wv + (size_t)l * 1024 * 1024;
    const float* Wo_l = Wo + (size_t)l * 1024 * 1024;
    const float* W1_l = W1 + (size_t)l * 1024 * 4096;
    const float* W2_l = W2 + (size_t)l * 4096 * 1024;

    // fused QKV: weight planes contiguous [3072][1024] (stride WP = 1M elems)
    concat3<<<12, 256, 0, stream>>>(bq + l * 1024, bk + l * 1024, bv + l * 1024, bcat);
    wsplit_t<<<wsQ, 256, 0, stream>>>(Wq_l, Wth, Wtl, 1024, 1024);
    wsplit_t<<<wsQ, 256, 0, stream>>>(Wk_l, Wth + WP, Wtl + WP, 1024, 1024);
    wsplit_t<<<wsQ, 256, 0, stream>>>(Wv_l, Wth + 2 * WP, Wtl + 2 * WP, 1024, 1024);
    gemm_mfma<5, 4><<<gQKV, 256, 0, stream>>>(Xh, Xl, Wth, Wtl, bcat,
        nullptr, nullptr, PLh, PLl, 4096, 3072, 1024);

    attn_mfma<<<dim3(32, 8), 512, 0, stream>>>(PLh, PLl, PLh + QK, PLl + QK,
        PLh + 2 * QK, PLl + 2 * QK, amask, rel + (size_t)l * 1023 * 32, CTXh, CTXl);

    wsplit_t<<<wsQ, 256, 0, stream>>>(Wo_l, Wth, Wtl, 1024, 1024);
    gemm_mfma<2, 2><<<gN64, 256, 0, stream>>>(CTXh, CTXl, Wth, Wtl, bo + l * 1024,
        x_in, buf_t, nullptr, nullptr, 4096, 1024, 1024);
    ln_kernel<<<4096, 256, 0, stream>>>(buf_t, ln1g + l * 1024, ln1b + l * 1024,
                                        buf_h1, H1h, H1l);

    wsplit_t<<<dim3(4096 / 32, 1024 / 32), 256, 0, stream>>>(W1_l, Wth, Wtl, 1024, 4096);
    gemm_mfma<1, 4><<<gF1, 256, 0, stream>>>(H1h, H1l, Wth, Wtl, b1 + l * 4096,
        nullptr, nullptr, F1h, F1l, 4096, 4096, 1024);
    wsplit_t<<<dim3(1024 / 32, 4096 / 32), 256, 0, stream>>>(W2_l, Wth, Wtl, 4096, 1024);
    gemm_mfma<2, 2><<<gN64, 256, 0, stream>>>(F1h, F1l, Wth, Wtl, b2 + l * 1024,
        buf_h1, buf_t, nullptr, nullptr, 4096, 1024, 4096);
    ln_kernel<<<4096, 256, 0, stream>>>(buf_t, ln2g + l * 1024, ln2b + l * 1024,
                                        buf_x, Xh, Xl);
    x_in = buf_x;
  }

  pool_kernel<<<dim3(8, 8), 128, 0, stream>>>(buf_x, amask, pooled);
  pool_gemm_kernel<<<32, 256, 0, stream>>>(pooled, poolW, poolb, pool_h);
  ln_kernel<<<8, 256, 0, stream>>>(pool_h, plng, plnb, pool_h2, nullptr, nullptr);
  cls_kernel<<<8, 64, 0, stream>>>(pool_h2, clsW, clsb, (float*)d_out);
}

// Round 6
// 1610.568 us; speedup vs baseline: 4.6844x; 1.7008x over previous
//
#include <hip/hip_runtime.h>
#include <math.h>

typedef __attribute__((ext_vector_type(8))) _Float16 f16x8;
typedef __attribute__((ext_vector_type(4))) float f32x4;

// ---------- fp16 helpers ----------
__device__ __forceinline__ ushort f2h(float x) {
  union { _Float16 h; ushort u; } c;
  c.h = (_Float16)x;
  return c.u;
}
__device__ __forceinline__ void gl_lds16(const ushort* g, ushort* l) {
  __builtin_amdgcn_global_load_lds(
      (const __attribute__((address_space(1))) unsigned int*)g,
      (__attribute__((address_space(3))) unsigned int*)l, 16, 0, 0);
}
__device__ __forceinline__ f32x4 mfma16(f16x8 a, f16x8 b, f32x4 c) {
  return __builtin_amdgcn_mfma_f32_16x16x32_f16(a, b, c, 0, 0, 0);
}

// ---------- block-wide sum reduce (256 threads = 4 waves) ----------
__device__ __forceinline__ float block_reduce_sum(float v, float* sb) {
#pragma unroll
  for (int o = 32; o > 0; o >>= 1) v += __shfl_down(v, o, 64);
  const int t = threadIdx.x;
  if ((t & 63) == 0) sb[t >> 6] = v;
  __syncthreads();
  v = sb[0] + sb[1] + sb[2] + sb[3];
  __syncthreads();
  return v;
}

// ---------- activation cast: fp32 -> fp16 plane ----------
__global__ __launch_bounds__(256) void acast(const float* __restrict__ X,
                                             ushort* __restrict__ H, int n4) {
  const int i = blockIdx.x * 256 + threadIdx.x;
  if (i >= n4) return;
  const float4 x = ((const float4*)X)[i];
  ushort4 h;
  h.x = f2h(x.x); h.y = f2h(x.y); h.z = f2h(x.z); h.w = f2h(x.w);
  ((ushort4*)H)[i] = h;
}

// ---------- bias concat for fused QKV ----------
__global__ __launch_bounds__(256) void concat3(const float* __restrict__ a,
                                               const float* __restrict__ b,
                                               const float* __restrict__ c,
                                               float* __restrict__ o) {
  const int i = blockIdx.x * 256 + threadIdx.x;  // 0..3071
  o[i] = i < 1024 ? a[i] : (i < 2048 ? b[i - 1024] : c[i - 2048]);
}

// ---------- weight transpose+cast: W[K,N] fp32 -> T [N,K] fp16 ----------
__global__ __launch_bounds__(256) void wcast_t(const float* __restrict__ W,
                                               ushort* __restrict__ T,
                                               int K, int N) {
  __shared__ float s[32][33];
  const int tx = threadIdx.x & 31, ty = threadIdx.x >> 5;
  const int n0 = blockIdx.x * 32, k0 = blockIdx.y * 32;
#pragma unroll
  for (int i = 0; i < 4; ++i)
    s[ty + i * 8][tx] = W[(size_t)(k0 + ty + i * 8) * N + n0 + tx];
  __syncthreads();
#pragma unroll
  for (int i = 0; i < 4; ++i) {
    const int n = ty + i * 8;
    T[(size_t)(n0 + n) * K + k0 + tx] = f2h(s[tx][n]);
  }
}

// ---------- fp16 MFMA GEMM, 128 x (NF*32) tile, BK=32, dbuf 2-phase ----------
// NF = per-wave N fragments (2 -> BN=64, 4 -> BN=128). 4 waves as 2x2.
// EPI: 1 bias+GELU->plane | 2 bias+res->C |
//      5 QKV fused: col<2048 -> Q/K planes [2][4096][1024]; col>=2048 ->
//        transposed V plane at O+8M: [(b*32+h)*32+d][512]
template <int EPI, int NF>
__global__ __launch_bounds__(256, NF == 4 ? 2 : 3) void gemm_mfma(
    const ushort* __restrict__ A, const ushort* __restrict__ B,
    const float* __restrict__ bias, const float* __restrict__ res,
    float* __restrict__ C, ushort* __restrict__ O, int M, int N, int K) {
  __shared__ __align__(16) ushort sA[2][4096], sB[2][NF * 1024];
  const int t = threadIdx.x, w = t >> 6, lane = t & 63;
  const int llo = lane & 15, lhi = lane >> 4;
  const int wm = w >> 1, wn = w & 1;

  // XCD-aware bijective swizzle (all our grids have nwg % 8 == 0)
  const int gx = gridDim.x;
  int wg = blockIdx.y * gx + blockIdx.x;
  const int nwg = gx * gridDim.y;
  wg = (wg & 7) * (nwg >> 3) + (wg >> 3);
  const int bm = (wg / gx) * 128, bn = (wg % gx) * (NF * 32);

  const ushort* pA0 = A + (size_t)(bm + lane) * K + w * 8;
  const ushort* pA1 = pA0 + (size_t)64 * K;
  const ushort* pB0 = B + (size_t)(bn + lane) * K + w * 8;
  const ushort* pB1 = (NF == 4) ? pB0 + (size_t)64 * K : pB0;

  auto STAGE = [&](int buf, int k0) {
    gl_lds16(pA0 + k0, &sA[buf][w * 1024]);
    gl_lds16(pA1 + k0, &sA[buf][w * 1024 + 512]);
    if (NF == 4) {
      gl_lds16(pB0 + k0, &sB[buf][w * 1024]);
      gl_lds16(pB1 + k0, &sB[buf][w * 1024 + 512]);
    } else {
      gl_lds16(pB0 + k0, &sB[buf][w * 512]);
    }
  };

  f32x4 acc[4][NF] = {};
  const int NT = K >> 5;
  STAGE(0, 0);
  __syncthreads();  // vmcnt(0) drain + barrier: tile 0 ready
  int cur = 0;
  for (int kt = 0; kt < NT; ++kt) {
    if (kt + 1 < NT) STAGE(cur ^ 1, (kt + 1) << 5);  // prefetch next tile
    f16x8 a[4], bf[NF];
#pragma unroll
    for (int f = 0; f < 4; ++f)
      a[f] = *(const f16x8*)&sA[cur][lhi * 1024 + (wm * 64 + f * 16 + llo) * 8];
#pragma unroll
    for (int f = 0; f < NF; ++f)
      bf[f] = *(const f16x8*)&sB[cur][lhi * (NF * 256) +
                                      (wn * (NF * 16) + f * 16 + llo) * 8];
#pragma unroll
    for (int fm = 0; fm < 4; ++fm)
#pragma unroll
      for (int fn = 0; fn < NF; ++fn)
        acc[fm][fn] = mfma16(a[fm], bf[fn], acc[fm][fn]);
    __syncthreads();  // vmcnt(0): prefetch complete (AFTER compute) + barrier
    cur ^= 1;
  }

  // epilogue: C/D map col = lane&15, row = (lane>>4)*4 + r
#pragma unroll
  for (int fm = 0; fm < 4; ++fm) {
    const int row0 = bm + wm * 64 + fm * 16 + lhi * 4;
#pragma unroll
    for (int fn = 0; fn < NF; ++fn) {
      const int col = bn + wn * (NF * 16) + fn * 16 + llo;
      const float bc = bias[col];
      if (EPI == 5) {
        if (col < 2048) {
          const size_t base = (size_t)(col >> 10) * (4096 * 1024) + (col & 1023);
#pragma unroll
          for (int r = 0; r < 4; ++r)
            O[base + (size_t)(row0 + r) * 1024] = f2h(acc[fm][fn][r] + bc);
        } else {
          const int c = col - 2048;
          ushort4 vh;
#pragma unroll
          for (int r = 0; r < 4; ++r) ((ushort*)&vh)[r] = f2h(acc[fm][fn][r] + bc);
          const size_t o = (size_t)8 * 1024 * 1024 +
              ((size_t)(((row0 >> 9) * 32 + (c >> 5)) * 32 + (c & 31))) * 512 +
              (row0 & 511);
          *(ushort4*)(O + o) = vh;
        }
      } else {
#pragma unroll
        for (int r = 0; r < 4; ++r) {
          const size_t o = (size_t)(row0 + r) * N + col;
          float v = acc[fm][fn][r] + bc;
          if (EPI == 2) {
            v += res[o];
            C[o] = v;
          } else {  // EPI == 1: GELU -> fp16 plane
            v = 0.5f * v * (1.f + erff(v * 0.70710678118654752f));
            O[o] = f2h(v);
          }
        }
      }
    }
  }
}

// ---------- fp16 MFMA flash attention per (b,h,zhalf): 512 threads ----------
// Swapped QK^T (S^T = K.Q^T); K slab [oct4][512][8]; V^T slab [koct64][32][8].
__global__ __launch_bounds__(512, 2) void attn_mfma(
    const ushort* __restrict__ Qg, const ushort* __restrict__ Kg,
    const ushort* __restrict__ Vg, const float* __restrict__ mask,
    const float* __restrict__ rel_l, ushort* __restrict__ Cg) {
  __shared__ __align__(16) ushort sK[16384], sV[16384];
  __shared__ __align__(16) ushort sP[5120];
  __shared__ float rel_s[1024];
  __shared__ float madd[512];

  const int h = blockIdx.x, b = blockIdx.y, z = blockIdx.z;
  const int t = threadIdx.x, w = t >> 6, lane = t & 63;
  const int llo = lane & 15, lhi = lane >> 4;
  const float SCALE = 0.17677669529663687f;  // 1/sqrt(32)

#pragma unroll
  for (int it = 0; it < 4; ++it) {
    const int task = t + it * 512;  // 0..2047
    const int s = task >> 2, oct = task & 3;
    const size_t g = (size_t)(b * 512 + s) * 1024 + h * 32 + oct * 8;
    *(uint4*)&sK[oct * 4096 + s * 8] = *(const uint4*)(Kg + g);
  }
#pragma unroll
  for (int it = 0; it < 4; ++it) {
    const int task = t + it * 512;  // 0..2047
    const int d = task >> 6, ko = task & 63;
    const size_t g = (size_t)((b * 32 + h) * 32 + d) * 512 + ko * 8;
    *(uint4*)&sV[ko * 256 + d * 8] = *(const uint4*)(Vg + g);
  }
  for (int i = t; i < 1023; i += 512) rel_s[i] = rel_l[(size_t)i * 32 + h];
  for (int i = t; i < 512; i += 512) madd[i] = (1.f - mask[b * 512 + i]) * -1e9f;
  __syncthreads();

  uint* wP = (uint*)(sP + w * 640 + llo * 40);
  const ushort* rP = sP + w * 640 + llo * 40;

  for (int qt = 0; qt < 2; ++qt) {
    const int q = z * 256 + w * 32 + qt * 16 + llo;
    const size_t qg = (size_t)(b * 512 + q) * 1024 + h * 32 + lhi * 8;
    const f16x8 fQ = *(const f16x8*)(Qg + qg);
    float m = -INFINITY, l = 0.f;
    f32x4 acc0 = {0.f, 0.f, 0.f, 0.f};
    f32x4 acc1 = {0.f, 0.f, 0.f, 0.f};

    for (int kt2 = 0; kt2 < 16; ++kt2) {
      float p[8];
      float tm = -INFINITY;
#pragma unroll
      for (int sub = 0; sub < 2; ++sub) {
        const int kt = kt2 * 2 + sub;
        const f16x8 fK = *(const f16x8*)&sK[lhi * 4096 + (kt * 16 + llo) * 8];
        f32x4 s4 = {0.f, 0.f, 0.f, 0.f};
        s4 = mfma16(fK, fQ, s4);
#pragma unroll
        for (int r = 0; r < 4; ++r) {
          const int k = kt * 16 + lhi * 4 + r;
          const float sv = (s4[r] + rel_s[q - k + 511]) * SCALE + madd[k];
          p[sub * 4 + r] = sv;
          tm = fmaxf(tm, sv);
        }
      }
      tm = fmaxf(tm, __shfl_xor(tm, 16));
      tm = fmaxf(tm, __shfl_xor(tm, 32));
      const float nm = fmaxf(m, tm);
      const float sc = __expf(m - nm);
      float ts = 0.f;
#pragma unroll
      for (int i = 0; i < 8; ++i) {
        p[i] = __expf(p[i] - nm);
        ts += p[i];
      }
      ts += __shfl_xor(ts, 16);
      ts += __shfl_xor(ts, 32);
      l = l * sc + ts;
      m = nm;
      acc0 *= sc;
      acc1 *= sc;
      // pack P into wave-private LDS in B-frag layout (fp16)
#pragma unroll
      for (int sub = 0; sub < 2; ++sub) {
        wP[sub * 8 + lhi * 2 + 0] =
            (uint)f2h(p[sub * 4 + 0]) | ((uint)f2h(p[sub * 4 + 1]) << 16);
        wP[sub * 8 + lhi * 2 + 1] =
            (uint)f2h(p[sub * 4 + 2]) | ((uint)f2h(p[sub * 4 + 3]) << 16);
      }
      const f16x8 fP = *(const f16x8*)(rP + lhi * 8);
      const int vb = (kt2 * 4 + lhi) * 256;
      const f16x8 fV0 = *(const f16x8*)&sV[vb + llo * 8];
      const f16x8 fV1 = *(const f16x8*)&sV[vb + (16 + llo) * 8];
      acc0 = mfma16(fV0, fP, acc0);
      acc1 = mfma16(fV1, fP, acc1);
    }

    const float invl = 1.f / l;
    const size_t ob = (size_t)(b * 512 + q) * 1024 + h * 32;
    ushort4 oh;
#pragma unroll
    for (int r = 0; r < 4; ++r) ((ushort*)&oh)[r] = f2h(acc0[r] * invl);
    *(ushort4*)(Cg + ob + lhi * 4) = oh;
#pragma unroll
    for (int r = 0; r < 4; ++r) ((ushort*)&oh)[r] = f2h(acc1[r] * invl);
    *(ushort4*)(Cg + ob + 16 + lhi * 4) = oh;
  }
}

// ---------- LayerNorm over rows of 1024 (+optional fp16 plane) ----------
__global__ __launch_bounds__(256) void ln_kernel(
    const float* __restrict__ X, const float* __restrict__ g,
    const float* __restrict__ bt, float* __restrict__ out,
    ushort* __restrict__ O) {
  __shared__ float sb[4];
  const int row = blockIdx.x, t = threadIdx.x;
  const float4 x = *(const float4*)&X[(size_t)row * 1024 + t * 4];
  const float s = block_reduce_sum(x.x + x.y + x.z + x.w, sb);
  const float mu = s * (1.f / 1024.f);
  const float dx = x.x - mu, dy = x.y - mu, dz = x.z - mu, dw = x.w - mu;
  const float ss = block_reduce_sum(dx * dx + dy * dy + dz * dz + dw * dw, sb);
  const float rs = rsqrtf(ss * (1.f / 1024.f) + 1e-12f);
  const float4 gv = *(const float4*)&g[t * 4];
  const float4 bv = *(const float4*)&bt[t * 4];
  float4 o;
  o.x = dx * rs * gv.x + bv.x;
  o.y = dy * rs * gv.y + bv.y;
  o.z = dz * rs * gv.z + bv.z;
  o.w = dw * rs * gv.w + bv.w;
  *(float4*)&out[(size_t)row * 1024 + t * 4] = o;
  if (O) {
    ushort4 vh;
    vh.x = f2h(o.x); vh.y = f2h(o.y); vh.z = f2h(o.z); vh.w = f2h(o.w);
    *(ushort4*)&O[(size_t)row * 1024 + t * 4] = vh;
  }
}

// ---------- pooling: mean + max + first token ----------
__global__ __launch_bounds__(128) void pool_kernel(
    const float* __restrict__ X, const float* __restrict__ mask,
    float* __restrict__ pooled) {
  const int b = blockIdx.y;
  const int col = blockIdx.x * 128 + threadIdx.x;
  float sum = 0.f, mx = -INFINITY, cnt = 0.f;
  for (int s = 0; s < 512; ++s) {
    const float v = X[(size_t)(b * 512 + s) * 1024 + col];
    const float mk = mask[b * 512 + s];
    sum = fmaf(v, mk, sum);
    cnt += mk;
    mx = fmaxf(mx, v + (1.f - mk) * -1e9f);
  }
  pooled[(size_t)b * 3072 + col] = sum / cnt;
  pooled[(size_t)b * 3072 + 1024 + col] = mx;
  pooled[(size_t)b * 3072 + 2048 + col] = X[(size_t)(b * 512) * 1024 + col];
}

// ---------- small pooled GEMM [8,3072]@[3072,1024] ----------
__global__ __launch_bounds__(256) void pool_gemm_kernel(
    const float* __restrict__ P, const float* __restrict__ W,
    const float* __restrict__ bias, float* __restrict__ out) {
  const int idx = blockIdx.x * 256 + threadIdx.x;
  const int b = idx >> 10, n = idx & 1023;
  const float* pr = P + (size_t)b * 3072;
  float a = 0.f;
  for (int k = 0; k < 3072; ++k) a = fmaf(pr[k], W[(size_t)k * 1024 + n], a);
  out[idx] = a + bias[n];
}

// ---------- classifier [8,1024]@[1024,20] ----------
__global__ __launch_bounds__(64) void cls_kernel(
    const float* __restrict__ X, const float* __restrict__ W,
    const float* __restrict__ bias, float* __restrict__ out) {
  const int b = blockIdx.x, n = threadIdx.x;
  if (n < 20) {
    float a = 0.f;
    for (int k = 0; k < 1024; ++k)
      a = fmaf(X[(size_t)b * 1024 + k], W[(size_t)k * 20 + n], a);
    out[b * 20 + n] = a + bias[n];
  }
}

extern "C" void kernel_launch(void* const* d_in, const int* in_sizes, int n_in,
                              void* d_out, int out_size, void* d_ws, size_t ws_size,
                              hipStream_t stream) {
  const float* hs    = (const float*)d_in[0];
  const float* amask = (const float*)d_in[1];
  const float* Wq    = (const float*)d_in[2];
  const float* bq    = (const float*)d_in[3];
  const float* Wk    = (const float*)d_in[4];
  const float* bk    = (const float*)d_in[5];
  const float* Wv    = (const float*)d_in[6];
  const float* bv    = (const float*)d_in[7];
  const float* Wo    = (const float*)d_in[8];
  const float* bo    = (const float*)d_in[9];
  const float* ln1g  = (const float*)d_in[10];
  const float* ln1b  = (const float*)d_in[11];
  const float* W1    = (const float*)d_in[12];
  const float* b1    = (const float*)d_in[13];
  const float* W2    = (const float*)d_in[14];
  const float* b2    = (const float*)d_in[15];
  const float* ln2g  = (const float*)d_in[16];
  const float* ln2b  = (const float*)d_in[17];
  const float* rel   = (const float*)d_in[18];
  const float* poolW = (const float*)d_in[19];
  const float* poolb = (const float*)d_in[20];
  const float* plng  = (const float*)d_in[21];
  const float* plnb  = (const float*)d_in[22];
  const float* clsW  = (const float*)d_in[23];
  const float* clsb  = (const float*)d_in[24];

  char* W = (char*)d_ws;
  const size_t MB = (size_t)1 << 20;
  const size_t QK = (size_t)4096 * 1024;  // activation plane stride (elements)
  const size_t WP = (size_t)1024 * 1024;  // weight plane stride (elements)
  float* buf_t  = (float*)(W + 0 * MB);   // 16MB fp32
  float* buf_h1 = (float*)(W + 16 * MB);  // 16MB fp32
  float* buf_x  = (float*)(W + 32 * MB);  // 16MB fp32
  ushort* PL  = (ushort*)(W + 48 * MB);   // Q(0..4M) K(4M..8M) V^T(8M..12M), 24MB
  ushort* CTX = (ushort*)(W + 72 * MB);   // 8MB; also next-layer X plane
  ushort* Xp  = CTX;
  ushort* H1  = (ushort*)(W + 80 * MB);   // 8MB
  ushort* F1  = (ushort*)(W + 88 * MB);   // 32MB
  ushort* Wt  = (ushort*)(W + 120 * MB);  // up to 6MB ([3072][1024] fp16)
  float* bcat = (float*)(W + 126 * MB);   // 12KB
  float* pooled  = (float*)(W + 127 * MB);
  float* pool_h  = pooled + 8 * 3072;
  float* pool_h2 = pool_h + 8 * 1024;

  const int n4act = (4096 * 1024) / 4;
  const dim3 gQKV(3072 / 128, 32);  // 768 blocks, NF=4
  const dim3 gN64(1024 / 64, 32);   // 512 blocks, NF=2 (Wo, FFN2)
  const dim3 gF1(4096 / 128, 32);   // 1024 blocks, NF=4
  const dim3 wsQ(1024 / 32, 1024 / 32);

  acast<<<n4act / 256, 256, 0, stream>>>(hs, Xp, n4act);

  const float* x_in = hs;
  for (int l = 0; l < 4; ++l) {
    const float* Wq_l = Wq + (size_t)l * 1024 * 1024;
    const float* Wk_l = Wk + (size_t)l * 1024 * 1024;
    const float* Wv_l = Wv + (size_t)l * 1024 * 1024;
    const float* Wo_l = Wo + (size_t)l * 1024 * 1024;
    const float* W1_l = W1 + (size_t)l * 1024 * 4096;
    const float* W2_l = W2 + (size_t)l * 4096 * 1024;

    // fused QKV: weight planes contiguous [3072][1024] (stride WP)
    concat3<<<12, 256, 0, stream>>>(bq + l * 1024, bk + l * 1024, bv + l * 1024, bcat);
    wcast_t<<<wsQ, 256, 0, stream>>>(Wq_l, Wt, 1024, 1024);
    wcast_t<<<wsQ, 256, 0, stream>>>(Wk_l, Wt + WP, 1024, 1024);
    wcast_t<<<wsQ, 256, 0, stream>>>(Wv_l, Wt + 2 * WP, 1024, 1024);
    gemm_mfma<5, 4><<<gQKV, 256, 0, stream>>>(Xp, Wt, bcat, nullptr, nullptr,
                                              PL, 4096, 3072, 1024);

    attn_mfma<<<dim3(32, 8, 2), 512, 0, stream>>>(
        PL, PL + QK, PL + 2 * QK, amask, rel + (size_t)l * 1023 * 32, CTX);

    wcast_t<<<wsQ, 256, 0, stream>>>(Wo_l, Wt, 1024, 1024);
    gemm_mfma<2, 2><<<gN64, 256, 0, stream>>>(CTX, Wt, bo + l * 1024, x_in,
                                              buf_t, nullptr, 4096, 1024, 1024);
    ln_kernel<<<4096, 256, 0, stream>>>(buf_t, ln1g + l * 1024, ln1b + l * 1024,
                                        buf_h1, H1);

    wcast_t<<<dim3(4096 / 32, 1024 / 32), 256, 0, stream>>>(W1_l, Wt, 1024, 4096);
    gemm_mfma<1, 4><<<gF1, 256, 0, stream>>>(H1, Wt, b1 + l * 4096, nullptr,
                                             nullptr, F1, 4096, 4096, 1024);
    wcast_t<<<dim3(1024 / 32, 4096 / 32), 256, 0, stream>>>(W2_l, Wt, 4096, 1024);
    gemm_mfma<2, 2><<<gN64, 256, 0, stream>>>(F1, Wt, b2 + l * 1024, buf_h1,
                                              buf_t, nullptr, 4096, 1024, 4096);
    ln_kernel<<<4096, 256, 0, stream>>>(buf_t, ln2g + l * 1024, ln2b + l * 1024,
                                        buf_x, Xp);
    x_in = buf_x;
  }

  pool_kernel<<<dim3(8, 8), 128, 0, stream>>>(buf_x, amask, pooled);
  pool_gemm_kernel<<<32, 256, 0, stream>>>(pooled, poolW, poolb, pool_h);
  ln_kernel<<<8, 256, 0, stream>>>(pool_h, plng, plnb, pool_h2, nullptr);
  cls_kernel<<<8, 64, 0, stream>>>(pool_h2, clsW, clsb, (float*)d_out);
}

// Round 7
// 1333.098 us; speedup vs baseline: 5.6594x; 1.2081x over previous
//
#include <hip/hip_runtime.h>
#include <math.h>

typedef __attribute__((ext_vector_type(8))) _Float16 f16x8;
typedef __attribute__((ext_vector_type(4))) float f32x4;

// ---------- fp16 helpers ----------
__device__ __forceinline__ ushort f2h(float x) {
  union { _Float16 h; ushort u; } c;
  c.h = (_Float16)x;
  return c.u;
}
__device__ __forceinline__ void gl_lds16(const ushort* g, ushort* l) {
  __builtin_amdgcn_global_load_lds(
      (const __attribute__((address_space(1))) unsigned int*)g,
      (__attribute__((address_space(3))) unsigned int*)l, 16, 0, 0);
}
__device__ __forceinline__ f32x4 mfma16(f16x8 a, f16x8 b, f32x4 c) {
  return __builtin_amdgcn_mfma_f32_16x16x32_f16(a, b, c, 0, 0, 0);
}

// ---------- block-wide sum reduce (256 threads = 4 waves) ----------
__device__ __forceinline__ float block_reduce_sum(float v, float* sb) {
#pragma unroll
  for (int o = 32; o > 0; o >>= 1) v += __shfl_down(v, o, 64);
  const int t = threadIdx.x;
  if ((t & 63) == 0) sb[t >> 6] = v;
  __syncthreads();
  v = sb[0] + sb[1] + sb[2] + sb[3];
  __syncthreads();
  return v;
}

// ---------- activation cast: fp32 -> fp16 plane ----------
__global__ __launch_bounds__(256) void acast(const float* __restrict__ X,
                                             ushort* __restrict__ H, int n4) {
  const int i = blockIdx.x * 256 + threadIdx.x;
  if (i >= n4) return;
  const float4 x = ((const float4*)X)[i];
  ushort4 h;
  h.x = f2h(x.x); h.y = f2h(x.y); h.z = f2h(x.z); h.w = f2h(x.w);
  ((ushort4*)H)[i] = h;
}

// ---------- bias concat for fused QKV ----------
__global__ __launch_bounds__(256) void concat3(const float* __restrict__ a,
                                               const float* __restrict__ b,
                                               const float* __restrict__ c,
                                               float* __restrict__ o) {
  const int i = blockIdx.x * 256 + threadIdx.x;  // 0..3071
  o[i] = i < 1024 ? a[i] : (i < 2048 ? b[i - 1024] : c[i - 2048]);
}

// ---------- weight transpose+cast: W[K,N] fp32 -> T [N,K] fp16 ----------
__global__ __launch_bounds__(256) void wcast_t(const float* __restrict__ W,
                                               ushort* __restrict__ T,
                                               int K, int N) {
  __shared__ float s[32][33];
  const int tx = threadIdx.x & 31, ty = threadIdx.x >> 5;
  const int n0 = blockIdx.x * 32, k0 = blockIdx.y * 32;
#pragma unroll
  for (int i = 0; i < 4; ++i)
    s[ty + i * 8][tx] = W[(size_t)(k0 + ty + i * 8) * N + n0 + tx];
  __syncthreads();
#pragma unroll
  for (int i = 0; i < 4; ++i) {
    const int n = ty + i * 8;
    T[(size_t)(n0 + n) * K + k0 + tx] = f2h(s[tx][n]);
  }
}

// ---------- fused QKV weight transpose (3x 1024x1024) ----------
__global__ __launch_bounds__(256) void wcast_t3(const float* __restrict__ W0,
                                                const float* __restrict__ W1,
                                                const float* __restrict__ W2,
                                                ushort* __restrict__ T) {
  __shared__ float s[32][33];
  const float* W = blockIdx.z == 0 ? W0 : (blockIdx.z == 1 ? W1 : W2);
  ushort* Tp = T + (size_t)blockIdx.z * 1024 * 1024;
  const int tx = threadIdx.x & 31, ty = threadIdx.x >> 5;
  const int n0 = blockIdx.x * 32, k0 = blockIdx.y * 32;
#pragma unroll
  for (int i = 0; i < 4; ++i)
    s[ty + i * 8][tx] = W[(size_t)(k0 + ty + i * 8) * 1024 + n0 + tx];
  __syncthreads();
#pragma unroll
  for (int i = 0; i < 4; ++i) {
    const int n = ty + i * 8;
    Tp[(size_t)(n0 + n) * 1024 + k0 + tx] = f2h(s[tx][n]);
  }
}

// ---------- fp16 MFMA GEMM, 128x128 tile, BK=32, dbuf 2-phase ----------
// 4 waves as 2x2, 16 MFMA per wave per K-step.
// EPI: 1 bias+GELU->plane O | 2 bias+res->C (KSPLIT: z0->C w/ bias+res, z1 raw->C2)
//      5 QKV fused: col<2048 -> Q/K planes [2][4096][1024]; col>=2048 ->
//        transposed V plane at O+8M: [(b*32+h)*32+d][512]
template <int EPI, int KSPLIT>
__global__ __launch_bounds__(256, 2) void gemm_mfma(
    const ushort* __restrict__ A, const ushort* __restrict__ B,
    const float* __restrict__ bias, const float* __restrict__ res,
    float* __restrict__ C, float* __restrict__ C2, ushort* __restrict__ O,
    int M, int N, int K) {
  __shared__ __align__(16) ushort sA[2][4096], sB[2][4096];
  const int t = threadIdx.x, w = t >> 6, lane = t & 63;
  const int llo = lane & 15, lhi = lane >> 4;
  const int wm = w >> 1, wn = w & 1;
  const int z = (KSPLIT > 1) ? blockIdx.z : 0;
  const int Ks = K / KSPLIT;

  // XCD-aware bijective swizzle over (x,y); all grids have nwg % 8 == 0
  const int gx = gridDim.x;
  int wg = blockIdx.y * gx + blockIdx.x;
  const int nwg = gx * gridDim.y;
  wg = (wg & 7) * (nwg >> 3) + (wg >> 3);
  const int bm = (wg / gx) * 128, bn = (wg % gx) * 128;

  const ushort* pA0 = A + (size_t)(bm + lane) * K + w * 8 + z * Ks;
  const ushort* pA1 = pA0 + (size_t)64 * K;
  const ushort* pB0 = B + (size_t)(bn + lane) * K + w * 8 + z * Ks;
  const ushort* pB1 = pB0 + (size_t)64 * K;

  auto STAGE = [&](int buf, int k0) {
    gl_lds16(pA0 + k0, &sA[buf][w * 1024]);
    gl_lds16(pA1 + k0, &sA[buf][w * 1024 + 512]);
    gl_lds16(pB0 + k0, &sB[buf][w * 1024]);
    gl_lds16(pB1 + k0, &sB[buf][w * 1024 + 512]);
  };

  f32x4 acc[4][4] = {};
  const int NT = Ks >> 5;
  STAGE(0, 0);
  __syncthreads();  // vmcnt(0) drain + barrier: tile 0 ready
  int cur = 0;
  for (int kt = 0; kt < NT; ++kt) {
    if (kt + 1 < NT) STAGE(cur ^ 1, (kt + 1) << 5);  // prefetch next tile
    f16x8 a[4], bfr[4];
#pragma unroll
    for (int f = 0; f < 4; ++f) {
      a[f] = *(const f16x8*)&sA[cur][lhi * 1024 + (wm * 64 + f * 16 + llo) * 8];
      bfr[f] = *(const f16x8*)&sB[cur][lhi * 1024 + (wn * 64 + f * 16 + llo) * 8];
    }
#pragma unroll
    for (int fm = 0; fm < 4; ++fm)
#pragma unroll
      for (int fn = 0; fn < 4; ++fn)
        acc[fm][fn] = mfma16(a[fm], bfr[fn], acc[fm][fn]);
    __syncthreads();  // vmcnt(0): prefetch complete (AFTER compute) + barrier
    cur ^= 1;
  }

  // epilogue: C/D map col = lane&15, row = (lane>>4)*4 + r
#pragma unroll
  for (int fm = 0; fm < 4; ++fm) {
    const int row0 = bm + wm * 64 + fm * 16 + lhi * 4;
#pragma unroll
    for (int fn = 0; fn < 4; ++fn) {
      const int col = bn + wn * 64 + fn * 16 + llo;
      const float bc = bias[col];
      if (EPI == 5) {
        if (col < 2048) {
          const size_t base = (size_t)(col >> 10) * (4096 * 1024) + (col & 1023);
#pragma unroll
          for (int r = 0; r < 4; ++r)
            O[base + (size_t)(row0 + r) * 1024] = f2h(acc[fm][fn][r] + bc);
        } else {
          const int c = col - 2048;
          ushort4 vh;
#pragma unroll
          for (int r = 0; r < 4; ++r) ((ushort*)&vh)[r] = f2h(acc[fm][fn][r] + bc);
          const size_t o = (size_t)8 * 1024 * 1024 +
              ((size_t)(((row0 >> 9) * 32 + (c >> 5)) * 32 + (c & 31))) * 512 +
              (row0 & 511);
          *(ushort4*)(O + o) = vh;
        }
      } else if (EPI == 2) {
#pragma unroll
        for (int r = 0; r < 4; ++r) {
          const size_t o = (size_t)(row0 + r) * N + col;
          if (KSPLIT == 1 || z == 0)
            C[o] = acc[fm][fn][r] + bc + res[o];
          else
            C2[o] = acc[fm][fn][r];
        }
      } else {  // EPI == 1: GELU -> fp16 plane
#pragma unroll
        for (int r = 0; r < 4; ++r) {
          const size_t o = (size_t)(row0 + r) * N + col;
          float v = acc[fm][fn][r] + bc;
          v = 0.5f * v * (1.f + erff(v * 0.70710678118654752f));
          O[o] = f2h(v);
        }
      }
    }
  }
}

// ---------- fp16 MFMA flash attention per (b,h,zhalf): 512 threads ----------
// Swapped QK^T (S^T = K.Q^T); K slab [oct4][512][8]; V^T slab [koct64][32][8].
__global__ __launch_bounds__(512, 2) void attn_mfma(
    const ushort* __restrict__ Qg, const ushort* __restrict__ Kg,
    const ushort* __restrict__ Vg, const float* __restrict__ mask,
    const float* __restrict__ rel_l, ushort* __restrict__ Cg) {
  __shared__ __align__(16) ushort sK[16384], sV[16384];
  __shared__ __align__(16) ushort sP[5120];
  __shared__ float rel_s[1024];
  __shared__ float madd[512];

  const int h = blockIdx.x, b = blockIdx.y, z = blockIdx.z;
  const int t = threadIdx.x, w = t >> 6, lane = t & 63;
  const int llo = lane & 15, lhi = lane >> 4;
  const float SCALE = 0.17677669529663687f;  // 1/sqrt(32)

#pragma unroll
  for (int it = 0; it < 4; ++it) {
    const int task = t + it * 512;  // 0..2047
    const int s = task >> 2, oct = task & 3;
    const size_t g = (size_t)(b * 512 + s) * 1024 + h * 32 + oct * 8;
    *(uint4*)&sK[oct * 4096 + s * 8] = *(const uint4*)(Kg + g);
  }
#pragma unroll
  for (int it = 0; it < 4; ++it) {
    const int task = t + it * 512;  // 0..2047
    const int d = task >> 6, ko = task & 63;
    const size_t g = (size_t)((b * 32 + h) * 32 + d) * 512 + ko * 8;
    *(uint4*)&sV[ko * 256 + d * 8] = *(const uint4*)(Vg + g);
  }
  for (int i = t; i < 1023; i += 512) rel_s[i] = rel_l[(size_t)i * 32 + h];
  for (int i = t; i < 512; i += 512) madd[i] = (1.f - mask[b * 512 + i]) * -1e9f;
  __syncthreads();

  uint* wP = (uint*)(sP + w * 640 + llo * 40);
  const ushort* rP = sP + w * 640 + llo * 40;

  for (int qt = 0; qt < 2; ++qt) {
    const int q = z * 256 + w * 32 + qt * 16 + llo;
    const size_t qg = (size_t)(b * 512 + q) * 1024 + h * 32 + lhi * 8;
    const f16x8 fQ = *(const f16x8*)(Qg + qg);
    float m = -INFINITY, l = 0.f;
    f32x4 acc0 = {0.f, 0.f, 0.f, 0.f};
    f32x4 acc1 = {0.f, 0.f, 0.f, 0.f};

    for (int kt2 = 0; kt2 < 16; ++kt2) {
      float p[8];
      float tm = -INFINITY;
#pragma unroll
      for (int sub = 0; sub < 2; ++sub) {
        const int kt = kt2 * 2 + sub;
        const f16x8 fK = *(const f16x8*)&sK[lhi * 4096 + (kt * 16 + llo) * 8];
        f32x4 s4 = {0.f, 0.f, 0.f, 0.f};
        s4 = mfma16(fK, fQ, s4);
#pragma unroll
        for (int r = 0; r < 4; ++r) {
          const int k = kt * 16 + lhi * 4 + r;
          const float sv = (s4[r] + rel_s[q - k + 511]) * SCALE + madd[k];
          p[sub * 4 + r] = sv;
          tm = fmaxf(tm, sv);
        }
      }
      tm = fmaxf(tm, __shfl_xor(tm, 16));
      tm = fmaxf(tm, __shfl_xor(tm, 32));
      const float nm = fmaxf(m, tm);
      const float sc = __expf(m - nm);
      float ts = 0.f;
#pragma unroll
      for (int i = 0; i < 8; ++i) {
        p[i] = __expf(p[i] - nm);
        ts += p[i];
      }
      ts += __shfl_xor(ts, 16);
      ts += __shfl_xor(ts, 32);
      l = l * sc + ts;
      m = nm;
      acc0 *= sc;
      acc1 *= sc;
      // pack P into wave-private LDS in B-frag layout (fp16)
#pragma unroll
      for (int sub = 0; sub < 2; ++sub) {
        wP[sub * 8 + lhi * 2 + 0] =
            (uint)f2h(p[sub * 4 + 0]) | ((uint)f2h(p[sub * 4 + 1]) << 16);
        wP[sub * 8 + lhi * 2 + 1] =
            (uint)f2h(p[sub * 4 + 2]) | ((uint)f2h(p[sub * 4 + 3]) << 16);
      }
      const f16x8 fP = *(const f16x8*)(rP + lhi * 8);
      const int vb = (kt2 * 4 + lhi) * 256;
      const f16x8 fV0 = *(const f16x8*)&sV[vb + llo * 8];
      const f16x8 fV1 = *(const f16x8*)&sV[vb + (16 + llo) * 8];
      acc0 = mfma16(fV0, fP, acc0);
      acc1 = mfma16(fV1, fP, acc1);
    }

    const float invl = 1.f / l;
    const size_t ob = (size_t)(b * 512 + q) * 1024 + h * 32;
    ushort4 oh;
#pragma unroll
    for (int r = 0; r < 4; ++r) ((ushort*)&oh)[r] = f2h(acc0[r] * invl);
    *(ushort4*)(Cg + ob + lhi * 4) = oh;
#pragma unroll
    for (int r = 0; r < 4; ++r) ((ushort*)&oh)[r] = f2h(acc1[r] * invl);
    *(ushort4*)(Cg + ob + 16 + lhi * 4) = oh;
  }
}

// ---------- LayerNorm over rows of 1024 (optional 2nd addend, fp16 plane) ----
__global__ __launch_bounds__(256) void ln_kernel(
    const float* __restrict__ X, const float* __restrict__ X2,
    const float* __restrict__ g, const float* __restrict__ bt,
    float* __restrict__ out, ushort* __restrict__ O) {
  __shared__ float sb[4];
  const int row = blockIdx.x, t = threadIdx.x;
  float4 x = *(const float4*)&X[(size_t)row * 1024 + t * 4];
  if (X2) {
    const float4 y = *(const float4*)&X2[(size_t)row * 1024 + t * 4];
    x.x += y.x; x.y += y.y; x.z += y.z; x.w += y.w;
  }
  const float s = block_reduce_sum(x.x + x.y + x.z + x.w, sb);
  const float mu = s * (1.f / 1024.f);
  const float dx = x.x - mu, dy = x.y - mu, dz = x.z - mu, dw = x.w - mu;
  const float ss = block_reduce_sum(dx * dx + dy * dy + dz * dz + dw * dw, sb);
  const float rs = rsqrtf(ss * (1.f / 1024.f) + 1e-12f);
  const float4 gv = *(const float4*)&g[t * 4];
  const float4 bv = *(const float4*)&bt[t * 4];
  float4 o;
  o.x = dx * rs * gv.x + bv.x;
  o.y = dy * rs * gv.y + bv.y;
  o.z = dz * rs * gv.z + bv.z;
  o.w = dw * rs * gv.w + bv.w;
  *(float4*)&out[(size_t)row * 1024 + t * 4] = o;
  if (O) {
    ushort4 vh;
    vh.x = f2h(o.x); vh.y = f2h(o.y); vh.z = f2h(o.z); vh.w = f2h(o.w);
    *(ushort4*)&O[(size_t)row * 1024 + t * 4] = vh;
  }
}

// ---------- pooling stage 1: s-split partials ----------
__global__ __launch_bounds__(128) void pool_part(
    const float* __restrict__ X, const float* __restrict__ mask,
    float* __restrict__ psum, float* __restrict__ pmax,
    float* __restrict__ pcnt) {
  const int cb = blockIdx.x, b = blockIdx.y, sb = blockIdx.z;
  const int col = cb * 128 + threadIdx.x;
  float sum = 0.f, mx = -INFINITY, cnt = 0.f;
  for (int i = 0; i < 128; ++i) {
    const int s = sb * 128 + i;
    const float v = X[(size_t)(b * 512 + s) * 1024 + col];
    const float mk = mask[b * 512 + s];
    sum = fmaf(v, mk, sum);
    cnt += mk;
    mx = fmaxf(mx, v + (1.f - mk) * -1e9f);
  }
  psum[(size_t)(sb * 8 + b) * 1024 + col] = sum;
  pmax[(size_t)(sb * 8 + b) * 1024 + col] = mx;
  if (cb == 0 && threadIdx.x == 0) pcnt[sb * 8 + b] = cnt;
}

// ---------- pooling finalize: mean + max + first token ----------
__global__ __launch_bounds__(256) void pool_fin(
    const float* __restrict__ X, const float* __restrict__ psum,
    const float* __restrict__ pmax, const float* __restrict__ pcnt,
    float* __restrict__ pooled) {
  const int idx = blockIdx.x * 256 + threadIdx.x;  // 0..8191
  const int b = idx >> 10, col = idx & 1023;
  float s = 0.f, m = -INFINITY, c = 0.f;
#pragma unroll
  for (int sb = 0; sb < 4; ++sb) {
    s += psum[(size_t)(sb * 8 + b) * 1024 + col];
    m = fmaxf(m, pmax[(size_t)(sb * 8 + b) * 1024 + col]);
    c += pcnt[sb * 8 + b];
  }
  pooled[(size_t)b * 3072 + col] = s / c;
  pooled[(size_t)b * 3072 + 1024 + col] = m;
  pooled[(size_t)b * 3072 + 2048 + col] = X[(size_t)(b * 512) * 1024 + col];
}

// ---------- pooled GEMM stage 1: split-K partials ----------
__global__ __launch_bounds__(256) void pgemm_part(
    const float* __restrict__ P, const float* __restrict__ W,
    float* __restrict__ part) {
  __shared__ float sP[8][192];
  __shared__ float sacc[256][9];
  const int nb = blockIdx.x, kb = blockIdx.y;
  const int t = threadIdx.x;
  const int k0 = kb * 192, n0 = nb * 64;
  for (int i = t; i < 1536; i += 256)
    sP[i / 192][i % 192] = P[(size_t)(i / 192) * 3072 + k0 + i % 192];
  __syncthreads();
  const int n = t & 63, kq = t >> 6;
  float acc[8] = {};
  for (int kk = 0; kk < 48; ++kk) {
    const int k = kq * 48 + kk;
    const float wv = W[(size_t)(k0 + k) * 1024 + n0 + n];
#pragma unroll
    for (int b = 0; b < 8; ++b) acc[b] = fmaf(sP[b][k], wv, acc[b]);
  }
#pragma unroll
  for (int b = 0; b < 8; ++b) sacc[t][b] = acc[b];
  __syncthreads();
  for (int p = t; p < 512; p += 256) {
    const int b = p >> 6, nn = p & 63;
    const float v = sacc[nn][b] + sacc[64 + nn][b] + sacc[128 + nn][b] +
                    sacc[192 + nn][b];
    part[((size_t)kb * 8 + b) * 1024 + n0 + nn] = v;
  }
}

// ---------- pooled GEMM finalize ----------
__global__ __launch_bounds__(256) void pgemm_fin(
    const float* __restrict__ part, const float* __restrict__ bias,
    float* __restrict__ out) {
  const int idx = blockIdx.x * 256 + threadIdx.x;  // 0..8191
  const int b = idx >> 10, n = idx & 1023;
  float v = bias[n];
#pragma unroll
  for (int kb = 0; kb < 16; ++kb) v += part[((size_t)kb * 8 + b) * 1024 + n];
  out[(size_t)b * 1024 + n] = v;
}

// ---------- classifier: one block per (n,b), wave-reduce over K ----------
__global__ __launch_bounds__(64) void cls_kernel(
    const float* __restrict__ X, const float* __restrict__ W,
    const float* __restrict__ bias, float* __restrict__ out) {
  const int n = blockIdx.x, b = blockIdx.y, lane = threadIdx.x;
  float a = 0.f;
#pragma unroll
  for (int i = 0; i < 16; ++i) {
    const int k = lane + i * 64;
    a = fmaf(X[(size_t)b * 1024 + k], W[(size_t)k * 20 + n], a);
  }
#pragma unroll
  for (int o = 32; o > 0; o >>= 1) a += __shfl_down(a, o, 64);
  if (lane == 0) out[b * 20 + n] = a + bias[n];
}

extern "C" void kernel_launch(void* const* d_in, const int* in_sizes, int n_in,
                              void* d_out, int out_size, void* d_ws, size_t ws_size,
                              hipStream_t stream) {
  const float* hs    = (const float*)d_in[0];
  const float* amask = (const float*)d_in[1];
  const float* Wq    = (const float*)d_in[2];
  const float* bq    = (const float*)d_in[3];
  const float* Wk    = (const float*)d_in[4];
  const float* bk    = (const float*)d_in[5];
  const float* Wv    = (const float*)d_in[6];
  const float* bv    = (const float*)d_in[7];
  const float* Wo    = (const float*)d_in[8];
  const float* bo    = (const float*)d_in[9];
  const float* ln1g  = (const float*)d_in[10];
  const float* ln1b  = (const float*)d_in[11];
  const float* W1    = (const float*)d_in[12];
  const float* b1    = (const float*)d_in[13];
  const float* W2    = (const float*)d_in[14];
  const float* b2    = (const float*)d_in[15];
  const float* ln2g  = (const float*)d_in[16];
  const float* ln2b  = (const float*)d_in[17];
  const float* rel   = (const float*)d_in[18];
  const float* poolW = (const float*)d_in[19];
  const float* poolb = (const float*)d_in[20];
  const float* plng  = (const float*)d_in[21];
  const float* plnb  = (const float*)d_in[22];
  const float* clsW  = (const float*)d_in[23];
  const float* clsb  = (const float*)d_in[24];

  char* W = (char*)d_ws;
  const size_t MB = (size_t)1 << 20;
  const size_t QK = (size_t)4096 * 1024;  // Q/K plane stride (elements)
  float* buf_t  = (float*)(W + 0 * MB);    // 16MB fp32
  float* buf_t2 = (float*)(W + 16 * MB);   // 16MB fp32 (split-K partials)
  float* buf_h1 = (float*)(W + 32 * MB);   // 16MB fp32
  float* buf_x  = (float*)(W + 48 * MB);   // 16MB fp32
  ushort* PL  = (ushort*)(W + 64 * MB);    // Q(0..4M) K(4..8M) V^T(8..12M), 24MB
  ushort* CTX = (ushort*)(W + 88 * MB);    // 8MB; also next-layer X plane
  ushort* Xp  = CTX;
  ushort* H1  = (ushort*)(W + 96 * MB);    // 8MB
  ushort* F1  = (ushort*)(W + 104 * MB);   // 32MB
  ushort* Wt  = (ushort*)(W + 136 * MB);   // 6MB ([3072][1024] fp16)
  float* bcat = (float*)(W + 142 * MB);    // 12KB
  float* sm   = (float*)(W + 143 * MB);    // small-buffer region (<1.5MB)
  float* pooled  = sm;                     // 8*3072
  float* pool_h  = pooled + 8 * 3072;      // 8*1024
  float* pool_h2 = pool_h + 8 * 1024;      // 8*1024
  float* pcnt    = pool_h2 + 8 * 1024;     // 32
  float* psum    = pcnt + 64;              // 4*8*1024
  float* pmax    = psum + 4 * 8 * 1024;    // 4*8*1024
  float* pgpart  = pmax + 4 * 8 * 1024;    // 16*8*1024

  const int n4act = (4096 * 1024) / 4;
  const dim3 gQKV(3072 / 128, 32);     // 768 blocks
  const dim3 gF1(4096 / 128, 32);      // 1024 blocks
  const dim3 gKS(1024 / 128, 32, 2);   // 512 blocks (Wo, FFN2 split-K)
  const dim3 wsQ3(32, 32, 3);

  acast<<<n4act / 256, 256, 0, stream>>>(hs, Xp, n4act);

  const float* x_in = hs;
  for (int l = 0; l < 4; ++l) {
    const float* Wq_l = Wq + (size_t)l * 1024 * 1024;
    const float* Wk_l = Wk + (size_t)l * 1024 * 1024;
    const float* Wv_l = Wv + (size_t)l * 1024 * 1024;
    const float* Wo_l = Wo + (size_t)l * 1024 * 1024;
    const float* W1_l = W1 + (size_t)l * 1024 * 4096;
    const float* W2_l = W2 + (size_t)l * 4096 * 1024;

    // fused QKV
    concat3<<<12, 256, 0, stream>>>(bq + l * 1024, bk + l * 1024, bv + l * 1024, bcat);
    wcast_t3<<<wsQ3, 256, 0, stream>>>(Wq_l, Wk_l, Wv_l, Wt);
    gemm_mfma<5, 1><<<gQKV, 256, 0, stream>>>(Xp, Wt, bcat, nullptr, nullptr,
                                              nullptr, PL, 4096, 3072, 1024);

    attn_mfma<<<dim3(32, 8, 2), 512, 0, stream>>>(
        PL, PL + QK, PL + 2 * QK, amask, rel + (size_t)l * 1023 * 32, CTX);

    wcast_t<<<dim3(32, 32), 256, 0, stream>>>(Wo_l, Wt, 1024, 1024);
    gemm_mfma<2, 2><<<gKS, 256, 0, stream>>>(CTX, Wt, bo + l * 1024, x_in,
                                             buf_t, buf_t2, nullptr, 4096, 1024, 1024);
    ln_kernel<<<4096, 256, 0, stream>>>(buf_t, buf_t2, ln1g + l * 1024,
                                        ln1b + l * 1024, buf_h1, H1);

    wcast_t<<<dim3(4096 / 32, 1024 / 32), 256, 0, stream>>>(W1_l, Wt, 1024, 4096);
    gemm_mfma<1, 1><<<gF1, 256, 0, stream>>>(H1, Wt, b1 + l * 4096, nullptr,
                                             nullptr, nullptr, F1, 4096, 4096, 1024);
    wcast_t<<<dim3(1024 / 32, 4096 / 32), 256, 0, stream>>>(W2_l, Wt, 4096, 1024);
    gemm_mfma<2, 2><<<gKS, 256, 0, stream>>>(F1, Wt, b2 + l * 1024, buf_h1,
                                             buf_t, buf_t2, nullptr, 4096, 1024, 4096);
    ln_kernel<<<4096, 256, 0, stream>>>(buf_t, buf_t2, ln2g + l * 1024,
                                        ln2b + l * 1024, buf_x, Xp);
    x_in = buf_x;
  }

  pool_part<<<dim3(8, 8, 4), 128, 0, stream>>>(buf_x, amask, psum, pmax, pcnt);
  pool_fin<<<32, 256, 0, stream>>>(buf_x, psum, pmax, pcnt, pooled);
  pgemm_part<<<dim3(16, 16), 256, 0, stream>>>(pooled, poolW, pgpart);
  pgemm_fin<<<32, 256, 0, stream>>>(pgpart, poolb, pool_h);
  ln_kernel<<<8, 256, 0, stream>>>(pool_h, nullptr, plng, plnb, pool_h2, nullptr);
  cls_kernel<<<dim3(20, 8), 64, 0, stream>>>(pool_h2, clsW, clsb, (float*)d_out);
}